// Round 1
// baseline (62928.516 us; speedup 1.0000x reference)
//
#include <hip/hip_runtime.h>
#include <cstdint>
#include <cmath>

// FCClassifier predictive-coding net, MI355X.
// sizes [3072,4096,4096,2048,1000], B=1024, 20 steps, gamma=0.1, noise 0.034*temp.
// Round 1: fp32 correctness baseline. Exact JAX threefry2x32 noise reproduction.

#define B_ROWS 1024
#define STEPS 20
#define GAMMA_F 0.1f
#define NOISE_SCALE_F 0.034f

// ---------------- threefry2x32 (matches jax._src.prng.threefry2x32) -------------
__host__ __device__ __forceinline__ uint32_t rotl32(uint32_t v, int r) {
  return (v << r) | (v >> (32 - r));
}

#define TF_ROUND(r) { x0 += x1; x1 = rotl32(x1, r); x1 ^= x0; }

__host__ __device__ __forceinline__ void tf2x32(uint32_t k0, uint32_t k1,
                                                uint32_t& x0, uint32_t& x1) {
  const uint32_t k2 = k0 ^ k1 ^ 0x1BD11BDAu;
  x0 += k0; x1 += k1;
  TF_ROUND(13) TF_ROUND(15) TF_ROUND(26) TF_ROUND(6)
  x0 += k1; x1 += k2 + 1u;
  TF_ROUND(17) TF_ROUND(29) TF_ROUND(16) TF_ROUND(24)
  x0 += k2; x1 += k0 + 2u;
  TF_ROUND(13) TF_ROUND(15) TF_ROUND(26) TF_ROUND(6)
  x0 += k0; x1 += k1 + 3u;
  TF_ROUND(17) TF_ROUND(29) TF_ROUND(16) TF_ROUND(24)
  x0 += k1; x1 += k2 + 4u;
  TF_ROUND(13) TF_ROUND(15) TF_ROUND(26) TF_ROUND(6)
  x0 += k2; x1 += k0 + 5u;
}

// XLA f32 ErfInv (Giles). Input |x| <= 0.99999994.
__device__ __forceinline__ float erfinv_f(float x) {
  float w = -log1pf(-x * x);
  float p;
  if (w < 5.0f) {
    w -= 2.5f;
    p = 2.81022636e-08f;
    p = fmaf(p, w, 3.43273939e-07f);
    p = fmaf(p, w, -3.5233877e-06f);
    p = fmaf(p, w, -4.39150654e-06f);
    p = fmaf(p, w, 0.00021858087f);
    p = fmaf(p, w, -0.00125372503f);
    p = fmaf(p, w, -0.00417768164f);
    p = fmaf(p, w, 0.246640727f);
    p = fmaf(p, w, 1.50140941f);
  } else {
    w = sqrtf(w) - 3.0f;
    p = -0.000200214257f;
    p = fmaf(p, w, 0.000100950558f);
    p = fmaf(p, w, 0.00134934322f);
    p = fmaf(p, w, -0.00367342844f);
    p = fmaf(p, w, 0.00573950773f);
    p = fmaf(p, w, -0.0076224613f);
    p = fmaf(p, w, 0.00943887047f);
    p = fmaf(p, w, 1.00167406f);
    p = fmaf(p, w, 2.83297682f);
  }
  return p * x;
}

// jax.random.normal element j of a flat array of even size Ntot, key (k0,k1):
// block b = j mod (Ntot/2); counters (b, b+Ntot/2); word = j / (Ntot/2).
__device__ __forceinline__ float jax_normal_at(uint32_t j, uint32_t half_n,
                                               uint32_t k0, uint32_t k1) {
  uint32_t blk, hi;
  if (j < half_n) { blk = j; hi = 0u; } else { blk = j - half_n; hi = 1u; }
  uint32_t x0 = blk, x1 = blk + half_n;
  tf2x32(k0, k1, x0, x1);
  uint32_t bits = hi ? x1 : x0;
  uint32_t fb = (bits >> 9) | 0x3f800000u;
  float f = __uint_as_float(fb) - 1.0f;         // [0, 1)
  const float LO = -0.99999994f;                // nextafter(-1,0) f32
  float u = fmaxf(LO, fmaf(f, 2.0f, LO));       // (hi-lo) rounds to 2.0f
  return 1.41421356237f * erfinv_f(u);
}

// ---------------- GEMM: 64x64 tile, BK=16, 256 threads, 4x4/thread --------------
// MODE 0: out = A @ W            (NN; W is K x N)   -- init forward
// MODE 1: out(es) = Xin - (tanh(A) @ W^T + bias) + nscale*noise   (NT; W is N x K)
// MODE 2: out(xs) += GAMMA*(-E + (A @ W)*(1 - tanh(out)^2))       (NN; W is K x N; E may be null)
template <int MODE>
__global__ __launch_bounds__(256)
void gemm_k(const float* __restrict__ A, const float* __restrict__ W,
            const float* __restrict__ bias, const float* __restrict__ Xin,
            const float* __restrict__ E, float* __restrict__ out,
            int M, int N, int K,
            uint32_t key0, uint32_t key1, float nscale) {
  __shared__ float As[16][68];  // [k][m], row stride 272B (16B aligned)
  __shared__ float Bs[16][68];  // [k][n]

  const int tid = threadIdx.x;
  const int m0 = blockIdx.y * 64;
  const int n0 = blockIdx.x * 64;
  const int tx = tid & 15;
  const int ty = tid >> 4;

  float acc[4][4] = {};

  for (int k0 = 0; k0 < K; k0 += 16) {
    // --- load A tile (M x K row-major) -> As[k][m], tanh applied in MODE 1
    {
      int m_l = tid >> 2;
      int k_l = (tid & 3) << 2;
      int gk = k0 + k_l;
      float4 v = make_float4(0.f, 0.f, 0.f, 0.f);
      if (gk < K) v = *reinterpret_cast<const float4*>(A + (size_t)(m0 + m_l) * K + gk);
      if (MODE == 1) {
        v.x = tanhf(v.x); v.y = tanhf(v.y); v.z = tanhf(v.z); v.w = tanhf(v.w);
      }
      As[k_l + 0][m_l] = v.x; As[k_l + 1][m_l] = v.y;
      As[k_l + 2][m_l] = v.z; As[k_l + 3][m_l] = v.w;
    }
    // --- load W tile -> Bs[k][n]
    if (MODE == 1) {
      // W is (N x K) row-major; Bs[k][n] = W[n][k]
      int n_l = tid >> 2;
      int k_l = (tid & 3) << 2;
      int gn = n0 + n_l, gk = k0 + k_l;
      float4 v = make_float4(0.f, 0.f, 0.f, 0.f);
      if (gn < N && gk < K) v = *reinterpret_cast<const float4*>(W + (size_t)gn * K + gk);
      Bs[k_l + 0][n_l] = v.x; Bs[k_l + 1][n_l] = v.y;
      Bs[k_l + 2][n_l] = v.z; Bs[k_l + 3][n_l] = v.w;
    } else {
      // W is (K x N) row-major; Bs[k][n] = W[k][n]
      int k_l = tid >> 4;
      int n_l = (tid & 15) << 2;
      int gk = k0 + k_l, gn = n0 + n_l;
      float4 v = make_float4(0.f, 0.f, 0.f, 0.f);
      if (gk < K && gn < N) v = *reinterpret_cast<const float4*>(W + (size_t)gk * N + gn);
      *reinterpret_cast<float4*>(&Bs[k_l][n_l]) = v;
    }
    __syncthreads();

#pragma unroll
    for (int kk = 0; kk < 16; ++kk) {
      float4 a = *reinterpret_cast<const float4*>(&As[kk][ty << 2]);
      float4 b = *reinterpret_cast<const float4*>(&Bs[kk][tx << 2]);
      acc[0][0] = fmaf(a.x, b.x, acc[0][0]); acc[0][1] = fmaf(a.x, b.y, acc[0][1]);
      acc[0][2] = fmaf(a.x, b.z, acc[0][2]); acc[0][3] = fmaf(a.x, b.w, acc[0][3]);
      acc[1][0] = fmaf(a.y, b.x, acc[1][0]); acc[1][1] = fmaf(a.y, b.y, acc[1][1]);
      acc[1][2] = fmaf(a.y, b.z, acc[1][2]); acc[1][3] = fmaf(a.y, b.w, acc[1][3]);
      acc[2][0] = fmaf(a.z, b.x, acc[2][0]); acc[2][1] = fmaf(a.z, b.y, acc[2][1]);
      acc[2][2] = fmaf(a.z, b.z, acc[2][2]); acc[2][3] = fmaf(a.z, b.w, acc[2][3]);
      acc[3][0] = fmaf(a.w, b.x, acc[3][0]); acc[3][1] = fmaf(a.w, b.y, acc[3][1]);
      acc[3][2] = fmaf(a.w, b.z, acc[3][2]); acc[3][3] = fmaf(a.w, b.w, acc[3][3]);
    }
    __syncthreads();
  }

  const uint32_t half_n = (uint32_t)(((size_t)M * (size_t)N) >> 1);
#pragma unroll
  for (int i = 0; i < 4; ++i) {
    int m = m0 + (ty << 2) + i;
#pragma unroll
    for (int jx = 0; jx < 4; ++jx) {
      int n = n0 + (tx << 2) + jx;
      if (n >= N) continue;
      size_t jf = (size_t)m * N + n;
      float a = acc[i][jx];
      if (MODE == 0) {
        out[jf] = a;
      } else if (MODE == 1) {
        float pred = a + bias[n];
        float z = jax_normal_at((uint32_t)jf, half_n, key0, key1);
        out[jf] = Xin[jf] - pred + z * nscale;
      } else {
        float x = out[jf];
        float t = tanhf(x);
        float e = (E != nullptr) ? E[jf] : 0.0f;
        out[jf] = x + GAMMA_F * fmaf(a, 1.0f - t * t, -e);
      }
    }
  }
}

// ---------------- launch ----------------
extern "C" void kernel_launch(void* const* d_in, const int* in_sizes, int n_in,
                              void* d_out, int out_size, void* d_ws, size_t ws_size,
                              hipStream_t stream) {
  const float* obs = (const float*)d_in[0];
  const float* W1  = (const float*)d_in[1];  // 3072 x 4096
  const float* b1  = (const float*)d_in[2];  // 3072
  const float* W2  = (const float*)d_in[3];  // 4096 x 4096
  const float* b2  = (const float*)d_in[4];  // 4096
  const float* W3  = (const float*)d_in[5];  // 4096 x 2048
  const float* b3  = (const float*)d_in[6];  // 4096
  const float* W4  = (const float*)d_in[7];  // 2048 x 1000
  const float* b4  = (const float*)d_in[8];  // 2048

  float* out = (float*)d_out;  // xs[4] lives here: 1024 x 1000
  float* ws = (float*)d_ws;

  const size_t S0 = 3072, S1 = 4096, S2 = 4096, S3 = 2048, S4 = 1000;
  float* xs1 = ws;
  float* xs2 = xs1 + (size_t)B_ROWS * S1;
  float* xs3 = xs2 + (size_t)B_ROWS * S2;
  float* es0 = xs3 + (size_t)B_ROWS * S3;
  float* es1 = es0 + (size_t)B_ROWS * S0;
  float* es2 = es1 + (size_t)B_ROWS * S1;
  float* es3 = es2 + (size_t)B_ROWS * S2;
  // total: (4096+4096+2048 + 3072+4096+4096+2048)*1024 floats = ~96.5 MB

  dim3 blk(256);
  auto grid_for = [](int N) { return dim3((N + 63) / 64, B_ROWS / 64); };

  // ---- init: bottom-up linear propagate (no tanh, no bias) ----
  gemm_k<0><<<grid_for(4096), blk, 0, stream>>>(obs, W1, nullptr, nullptr, nullptr, xs1,
                                                B_ROWS, 4096, 3072, 0u, 0u, 0.f);
  gemm_k<0><<<grid_for(4096), blk, 0, stream>>>(xs1, W2, nullptr, nullptr, nullptr, xs2,
                                                B_ROWS, 4096, 4096, 0u, 0u, 0.f);
  gemm_k<0><<<grid_for(2048), blk, 0, stream>>>(xs2, W3, nullptr, nullptr, nullptr, xs3,
                                                B_ROWS, 2048, 4096, 0u, 0u, 0.f);
  gemm_k<0><<<grid_for(1000), blk, 0, stream>>>(xs3, W4, nullptr, nullptr, nullptr, out,
                                                B_ROWS, 1000, 2048, 0u, 0u, 0.f);

  for (int i = 0; i < STEPS; ++i) {
    float scale = NOISE_SCALE_F * (1.0f - (float)i / (float)STEPS);
    // key chain: fold_in(fold_in(key(42), i), li); key(42) = [0,42]
    uint32_t s0 = 0u, s1 = (uint32_t)i;
    tf2x32(0u, 42u, s0, s1);
    uint32_t kk[4][2];
    for (int li = 0; li < 4; ++li) {
      uint32_t a = 0u, b = (uint32_t)li;
      tf2x32(s0, s1, a, b);
      kk[li][0] = a; kk[li][1] = b;
    }

    // ---- phase 1 (top-down): es[li] = xs[li] - (tanh(xs[li+1]) @ W_{li+1}^T + b) + noise
    gemm_k<1><<<grid_for(3072), blk, 0, stream>>>(xs1, W1, b1, obs, nullptr, es0,
                                                  B_ROWS, 3072, 4096, kk[0][0], kk[0][1], scale);
    gemm_k<1><<<grid_for(4096), blk, 0, stream>>>(xs2, W2, b2, xs1, nullptr, es1,
                                                  B_ROWS, 4096, 4096, kk[1][0], kk[1][1], scale);
    gemm_k<1><<<grid_for(4096), blk, 0, stream>>>(xs3, W3, b3, xs2, nullptr, es2,
                                                  B_ROWS, 4096, 2048, kk[2][0], kk[2][1], scale);
    gemm_k<1><<<grid_for(2048), blk, 0, stream>>>(out, W4, b4, xs3, nullptr, es3,
                                                  B_ROWS, 2048, 1000, kk[3][0], kk[3][1], scale);

    // ---- phase 2 (bottom-up): xs[li] += gamma*(-es[li] + (es[li-1] @ W_li)*(1-tanh(xs[li])^2))
    gemm_k<2><<<grid_for(4096), blk, 0, stream>>>(es0, W1, nullptr, nullptr, es1, xs1,
                                                  B_ROWS, 4096, 3072, 0u, 0u, 0.f);
    gemm_k<2><<<grid_for(4096), blk, 0, stream>>>(es1, W2, nullptr, nullptr, es2, xs2,
                                                  B_ROWS, 4096, 4096, 0u, 0u, 0.f);
    gemm_k<2><<<grid_for(2048), blk, 0, stream>>>(es2, W3, nullptr, nullptr, es3, xs3,
                                                  B_ROWS, 2048, 4096, 0u, 0u, 0.f);
    gemm_k<2><<<grid_for(1000), blk, 0, stream>>>(es3, W4, nullptr, nullptr, nullptr, out,
                                                  B_ROWS, 1000, 2048, 0u, 0u, 0.f);
  }
  // output = xs[4] already in d_out
}

// Round 2
// 62733.917 us; speedup vs baseline: 1.0031x; 1.0031x over previous
//
#include <hip/hip_runtime.h>
#include <cstdint>
#include <cmath>

// FCClassifier predictive-coding net, MI355X gfx950.
// Round 2: bf16 MFMA (16x16x32), 128x128 tiles, global_load_lds staging with
// XOR-swizzled LDS layout, fused per-phase launches. fp32 state + fp32 accum.
// Exact JAX threefry noise (validated round 1). fp32 fallback if ws too small.

#define B_ROWS 1024
#define STEPS 20
#define GAMMA_F 0.1f
#define NOISE_SCALE_F 0.034f

typedef float f32x4 __attribute__((ext_vector_type(4)));
typedef short sfrag __attribute__((ext_vector_type(8)));   // 8 bf16 in 4 VGPRs

// ---------------- threefry2x32 (matches jax._src.prng.threefry2x32) -------------
__host__ __device__ __forceinline__ uint32_t rotl32(uint32_t v, int r) {
  return (v << r) | (v >> (32 - r));
}
#define TF_ROUND(r) { x0 += x1; x1 = rotl32(x1, r); x1 ^= x0; }
__host__ __device__ __forceinline__ void tf2x32(uint32_t k0, uint32_t k1,
                                                uint32_t& x0, uint32_t& x1) {
  const uint32_t k2 = k0 ^ k1 ^ 0x1BD11BDAu;
  x0 += k0; x1 += k1;
  TF_ROUND(13) TF_ROUND(15) TF_ROUND(26) TF_ROUND(6)
  x0 += k1; x1 += k2 + 1u;
  TF_ROUND(17) TF_ROUND(29) TF_ROUND(16) TF_ROUND(24)
  x0 += k2; x1 += k0 + 2u;
  TF_ROUND(13) TF_ROUND(15) TF_ROUND(26) TF_ROUND(6)
  x0 += k0; x1 += k1 + 3u;
  TF_ROUND(17) TF_ROUND(29) TF_ROUND(16) TF_ROUND(24)
  x0 += k1; x1 += k2 + 4u;
  TF_ROUND(13) TF_ROUND(15) TF_ROUND(26) TF_ROUND(6)
  x0 += k2; x1 += k0 + 5u;
}

__device__ __forceinline__ float erfinv_f(float x) {
  float w = -log1pf(-x * x);
  float p;
  if (w < 5.0f) {
    w -= 2.5f;
    p = 2.81022636e-08f;
    p = fmaf(p, w, 3.43273939e-07f);
    p = fmaf(p, w, -3.5233877e-06f);
    p = fmaf(p, w, -4.39150654e-06f);
    p = fmaf(p, w, 0.00021858087f);
    p = fmaf(p, w, -0.00125372503f);
    p = fmaf(p, w, -0.00417768164f);
    p = fmaf(p, w, 0.246640727f);
    p = fmaf(p, w, 1.50140941f);
  } else {
    w = sqrtf(w) - 3.0f;
    p = -0.000200214257f;
    p = fmaf(p, w, 0.000100950558f);
    p = fmaf(p, w, 0.00134934322f);
    p = fmaf(p, w, -0.00367342844f);
    p = fmaf(p, w, 0.00573950773f);
    p = fmaf(p, w, -0.0076224613f);
    p = fmaf(p, w, 0.00943887047f);
    p = fmaf(p, w, 1.00167406f);
    p = fmaf(p, w, 2.83297682f);
  }
  return p * x;
}

__device__ __forceinline__ float jax_normal_at(uint32_t j, uint32_t half_n,
                                               uint32_t k0, uint32_t k1) {
  uint32_t blk, hi;
  if (j < half_n) { blk = j; hi = 0u; } else { blk = j - half_n; hi = 1u; }
  uint32_t x0 = blk, x1 = blk + half_n;
  tf2x32(k0, k1, x0, x1);
  uint32_t bits = hi ? x1 : x0;
  uint32_t fb = (bits >> 9) | 0x3f800000u;
  float f = __uint_as_float(fb) - 1.0f;
  const float LO = -0.99999994f;
  float u = fmaxf(LO, fmaf(f, 2.0f, LO));
  return 1.41421356237f * erfinv_f(u);
}

__device__ __forceinline__ short f2bf(float f) {
  uint32_t u = __float_as_uint(f);
  return (short)((u + 0x7fffu + ((u >> 16) & 1u)) >> 16);
}
__device__ __forceinline__ float b2f(short s) {
  return __uint_as_float(((uint32_t)(unsigned short)s) << 16);
}

// ---------------- MFMA core: C[128x128] at (m0,n0) = A(m,:) . Bt(n,:) ----------
// A: (rows x K) bf16 row-major; Bt: (N x K) bf16 row-major (k-contiguous both).
// LDS layout [row][32k] with 16B-chunk XOR swizzle: chunk c holds quad q = c ^ ((row>>1)&3).
__device__ __forceinline__ void mfma_block(const short* __restrict__ Ag,
                                           const short* __restrict__ Bg,
                                           int K, int m0, int n0,
                                           short* As, short* Bs,
                                           f32x4 (&acc)[4][4]) {
  const int tid = threadIdx.x;
  const int ln = tid & 63, wv = tid >> 6;
  const int wm = wv >> 1, wn = wv & 1;
  const int c16 = ln & 15, quad = ln >> 4;
  const int rl = ln >> 2, cl = ln & 3;

  for (int k0 = 0; k0 < K; k0 += 32) {
    __syncthreads();
#pragma unroll
    for (int half = 0; half < 2; ++half) {
      int Rb = wv * 32 + half * 16;
      int r = Rb + rl;
      int q = cl ^ ((r >> 1) & 3);
      const short* gA = Ag + (size_t)(m0 + r) * K + (k0 + q * 8);
      const short* gB = Bg + (size_t)(n0 + r) * K + (k0 + q * 8);
      __builtin_amdgcn_global_load_lds(
          (const __attribute__((address_space(1))) void*)gA,
          (__attribute__((address_space(3))) void*)(As + Rb * 32), 16u, 0, 0);
      __builtin_amdgcn_global_load_lds(
          (const __attribute__((address_space(1))) void*)gB,
          (__attribute__((address_space(3))) void*)(Bs + Rb * 32), 16u, 0, 0);
    }
    __syncthreads();
    sfrag af[4], bfr[4];
#pragma unroll
    for (int t = 0; t < 4; ++t) {
      int ra = wm * 64 + t * 16 + c16;
      af[t] = *(const sfrag*)(As + ra * 32 + ((quad ^ ((ra >> 1) & 3)) * 8));
      int rb = wn * 64 + t * 16 + c16;
      bfr[t] = *(const sfrag*)(Bs + rb * 32 + ((quad ^ ((rb >> 1) & 3)) * 8));
    }
#pragma unroll
    for (int mt = 0; mt < 4; ++mt)
#pragma unroll
      for (int nt = 0; nt < 4; ++nt)
        acc[mt][nt] = __builtin_amdgcn_mfma_f32_16x16x32_bf16(
            af[mt], bfr[nt], acc[mt][nt], 0, 0, 0);
  }
}

// ---------------- fused phase kernels ----------------
struct P1Args {
  const short *A[4], *W[4];
  const float *bias[4], *Xin[4];
  short *Eout[4];
  int N[4], K[4], cum[5];
  uint32_t key0[4], key1[4];
  float nscale;
};

__global__ __launch_bounds__(256) void phase1_k(P1Args p) {
  int b = blockIdx.x;
  int li = (b >= p.cum[2]) ? ((b >= p.cum[3]) ? 3 : 2) : ((b >= p.cum[1]) ? 1 : 0);
  int local = b - p.cum[li];
  int m0 = (local & 7) << 7, n0 = (local >> 3) << 7;
  const int N = p.N[li], K = p.K[li];

  __shared__ alignas(16) short As[128 * 32];
  __shared__ alignas(16) short Bs[128 * 32];
  f32x4 acc[4][4];
#pragma unroll
  for (int i = 0; i < 4; ++i)
#pragma unroll
    for (int j = 0; j < 4; ++j) acc[i][j] = (f32x4){0.f, 0.f, 0.f, 0.f};

  mfma_block(p.A[li], p.W[li], K, m0, n0, As, Bs, acc);

  const int tid = threadIdx.x, ln = tid & 63, wv = tid >> 6;
  const int wm = wv >> 1, wn = wv & 1, c16 = ln & 15, quad = ln >> 4;
  const float* Xin = p.Xin[li];
  const float* bias = p.bias[li];
  short* Eo = p.Eout[li];
  const uint32_t halfn = (uint32_t)(((size_t)B_ROWS * (size_t)N) >> 1);
  const uint32_t K0 = p.key0[li], K1 = p.key1[li];
  const float ns = p.nscale;
#pragma unroll
  for (int mt = 0; mt < 4; ++mt)
#pragma unroll
    for (int nt = 0; nt < 4; ++nt)
#pragma unroll
      for (int rg = 0; rg < 4; ++rg) {
        int m = m0 + wm * 64 + mt * 16 + quad * 4 + rg;
        int n = n0 + wn * 64 + nt * 16 + c16;
        size_t jf = (size_t)m * N + n;
        float pred = acc[mt][nt][rg] + bias[n];
        float z = jax_normal_at((uint32_t)jf, halfn, K0, K1);
        Eo[jf] = f2bf(Xin[jf] - pred + z * ns);
      }
}

struct P2Args {
  const short *A[4], *W[4], *E[4];
  float *Xs[4];
  short *T[4];
  int N[4], Nlog[4], K[4], cum[5];
};

__global__ __launch_bounds__(256) void phase2_k(P2Args p) {
  int b = blockIdx.x;
  int li = (b >= p.cum[2]) ? ((b >= p.cum[3]) ? 3 : 2) : ((b >= p.cum[1]) ? 1 : 0);
  int local = b - p.cum[li];
  int m0 = (local & 7) << 7, n0 = (local >> 3) << 7;
  const int N = p.N[li], Nlog = p.Nlog[li], K = p.K[li];

  __shared__ alignas(16) short As[128 * 32];
  __shared__ alignas(16) short Bs[128 * 32];
  f32x4 acc[4][4];
#pragma unroll
  for (int i = 0; i < 4; ++i)
#pragma unroll
    for (int j = 0; j < 4; ++j) acc[i][j] = (f32x4){0.f, 0.f, 0.f, 0.f};

  mfma_block(p.A[li], p.W[li], K, m0, n0, As, Bs, acc);

  const int tid = threadIdx.x, ln = tid & 63, wv = tid >> 6;
  const int wm = wv >> 1, wn = wv & 1, c16 = ln & 15, quad = ln >> 4;
  const short* Ep = p.E[li];
  float* Xs = p.Xs[li];
  short* T = p.T[li];
#pragma unroll
  for (int mt = 0; mt < 4; ++mt)
#pragma unroll
    for (int nt = 0; nt < 4; ++nt)
#pragma unroll
      for (int rg = 0; rg < 4; ++rg) {
        int m = m0 + wm * 64 + mt * 16 + quad * 4 + rg;
        int n = n0 + wn * 64 + nt * 16 + c16;
        if (n >= Nlog) continue;
        size_t jfX = (size_t)m * Nlog + n;
        float x = Xs[jfX];
        float t = tanhf(x);
        float e = Ep ? b2f(Ep[jfX]) : 0.f;
        float xn = x + GAMMA_F * fmaf(acc[mt][nt][rg], 1.0f - t * t, -e);
        Xs[jfX] = xn;
        T[(size_t)m * N + n] = f2bf(tanhf(xn));
      }
}

// init: C = A @ W (NN via WT buffer); writes xs fp32, x bf16 (optional), tanh bf16
__global__ __launch_bounds__(256) void gemm0_k(const short* __restrict__ A,
                                               const short* __restrict__ W,
                                               float* __restrict__ Xs,
                                               short* __restrict__ Xb,
                                               short* __restrict__ T,
                                               int Ngrid, int Nlog, int K) {
  int m0 = blockIdx.y << 7, n0 = blockIdx.x << 7;
  __shared__ alignas(16) short As[128 * 32];
  __shared__ alignas(16) short Bs[128 * 32];
  f32x4 acc[4][4];
#pragma unroll
  for (int i = 0; i < 4; ++i)
#pragma unroll
    for (int j = 0; j < 4; ++j) acc[i][j] = (f32x4){0.f, 0.f, 0.f, 0.f};

  mfma_block(A, W, K, m0, n0, As, Bs, acc);

  const int tid = threadIdx.x, ln = tid & 63, wv = tid >> 6;
  const int wm = wv >> 1, wn = wv & 1, c16 = ln & 15, quad = ln >> 4;
#pragma unroll
  for (int mt = 0; mt < 4; ++mt)
#pragma unroll
    for (int nt = 0; nt < 4; ++nt)
#pragma unroll
      for (int rg = 0; rg < 4; ++rg) {
        int m = m0 + wm * 64 + mt * 16 + quad * 4 + rg;
        int n = n0 + wn * 64 + nt * 16 + c16;
        if (n >= Nlog) continue;
        size_t jf = (size_t)m * Nlog + n;
        float x = acc[mt][nt][rg];
        Xs[jf] = x;
        if (Xb) Xb[jf] = f2bf(x);
        T[(size_t)m * Ngrid + n] = f2bf(tanhf(x));
      }
}

// ---------------- prep kernels ----------------
__global__ void cvt_k(const float* __restrict__ s, short* __restrict__ d, int n) {
  int i = blockIdx.x * blockDim.x + threadIdx.x;
  if (i < n) d[i] = f2bf(s[i]);
}

// dst (R x 2^sh) bf16 from src (R x Cs) fp32, zero pad cols >= Cs
__global__ void cvt_pad_k(const float* __restrict__ s, short* __restrict__ d,
                          int R, int Cs, int sh) {
  int i = blockIdx.x * blockDim.x + threadIdx.x;
  int total = R << sh;
  if (i >= total) return;
  int r = i >> sh, c = i & ((1 << sh) - 1);
  d[i] = (c < Cs) ? f2bf(s[(size_t)r * Cs + c]) : (short)0;
}

// dst[c*R + r] = bf16(src[r*C + c]); R multiple of 32; guard c < C
__global__ void transpose_k(const float* __restrict__ s, short* __restrict__ d,
                            int R, int C) {
  __shared__ float tile[32][33];
  int cb = blockIdx.x * 32, rb = blockIdx.y * 32;
  int tx = threadIdx.x & 31, ty = threadIdx.x >> 5;  // 256 threads
#pragma unroll
  for (int i = 0; i < 4; ++i) {
    int r = rb + ty + i * 8, c = cb + tx;
    if (c < C) tile[ty + i * 8][tx] = s[(size_t)r * C + c];
  }
  __syncthreads();
#pragma unroll
  for (int i = 0; i < 4; ++i) {
    int rr = rb + tx, cc = cb + ty + i * 8;
    if (cc < C) d[(size_t)cc * R + rr] = f2bf(tile[tx][ty + i * 8]);
  }
}

// zero t4 pad columns [1000,1024) for 1024 rows
__global__ void zero_pad_k(short* __restrict__ t4) {
  int i = blockIdx.x * blockDim.x + threadIdx.x;
  int r = i >> 5, c = i & 31;
  if (r < 1024 && c < 24) t4[(size_t)r * 1024 + 1000 + c] = 0;
}

// ================= fp32 fallback (round-1, proven) =================
template <int MODE>
__global__ __launch_bounds__(256)
void gemm_k(const float* __restrict__ A, const float* __restrict__ W,
            const float* __restrict__ bias, const float* __restrict__ Xin,
            const float* __restrict__ E, float* __restrict__ out,
            int M, int N, int K,
            uint32_t key0, uint32_t key1, float nscale) {
  __shared__ float As[16][68];
  __shared__ float Bs[16][68];
  const int tid = threadIdx.x;
  const int m0 = blockIdx.y * 64;
  const int n0 = blockIdx.x * 64;
  const int tx = tid & 15;
  const int ty = tid >> 4;
  float acc[4][4] = {};
  for (int k0 = 0; k0 < K; k0 += 16) {
    {
      int m_l = tid >> 2;
      int k_l = (tid & 3) << 2;
      int gk = k0 + k_l;
      float4 v = make_float4(0.f, 0.f, 0.f, 0.f);
      if (gk < K) v = *reinterpret_cast<const float4*>(A + (size_t)(m0 + m_l) * K + gk);
      if (MODE == 1) { v.x = tanhf(v.x); v.y = tanhf(v.y); v.z = tanhf(v.z); v.w = tanhf(v.w); }
      As[k_l + 0][m_l] = v.x; As[k_l + 1][m_l] = v.y;
      As[k_l + 2][m_l] = v.z; As[k_l + 3][m_l] = v.w;
    }
    if (MODE == 1) {
      int n_l = tid >> 2;
      int k_l = (tid & 3) << 2;
      int gn = n0 + n_l, gk = k0 + k_l;
      float4 v = make_float4(0.f, 0.f, 0.f, 0.f);
      if (gn < N && gk < K) v = *reinterpret_cast<const float4*>(W + (size_t)gn * K + gk);
      Bs[k_l + 0][n_l] = v.x; Bs[k_l + 1][n_l] = v.y;
      Bs[k_l + 2][n_l] = v.z; Bs[k_l + 3][n_l] = v.w;
    } else {
      int k_l = tid >> 4;
      int n_l = (tid & 15) << 2;
      int gk = k0 + k_l, gn = n0 + n_l;
      float4 v = make_float4(0.f, 0.f, 0.f, 0.f);
      if (gk < K && gn < N) v = *reinterpret_cast<const float4*>(W + (size_t)gk * N + gn);
      *reinterpret_cast<float4*>(&Bs[k_l][n_l]) = v;
    }
    __syncthreads();
#pragma unroll
    for (int kk = 0; kk < 16; ++kk) {
      float4 a = *reinterpret_cast<const float4*>(&As[kk][ty << 2]);
      float4 b = *reinterpret_cast<const float4*>(&Bs[kk][tx << 2]);
      acc[0][0] = fmaf(a.x, b.x, acc[0][0]); acc[0][1] = fmaf(a.x, b.y, acc[0][1]);
      acc[0][2] = fmaf(a.x, b.z, acc[0][2]); acc[0][3] = fmaf(a.x, b.w, acc[0][3]);
      acc[1][0] = fmaf(a.y, b.x, acc[1][0]); acc[1][1] = fmaf(a.y, b.y, acc[1][1]);
      acc[1][2] = fmaf(a.y, b.z, acc[1][2]); acc[1][3] = fmaf(a.y, b.w, acc[1][3]);
      acc[2][0] = fmaf(a.z, b.x, acc[2][0]); acc[2][1] = fmaf(a.z, b.y, acc[2][1]);
      acc[2][2] = fmaf(a.z, b.z, acc[2][2]); acc[2][3] = fmaf(a.z, b.w, acc[2][3]);
      acc[3][0] = fmaf(a.w, b.x, acc[3][0]); acc[3][1] = fmaf(a.w, b.y, acc[3][1]);
      acc[3][2] = fmaf(a.w, b.z, acc[3][2]); acc[3][3] = fmaf(a.w, b.w, acc[3][3]);
    }
    __syncthreads();
  }
  const uint32_t half_n = (uint32_t)(((size_t)M * N) >> 1);
#pragma unroll
  for (int i = 0; i < 4; ++i) {
    int m = m0 + (ty << 2) + i;
#pragma unroll
    for (int jx = 0; jx < 4; ++jx) {
      int n = n0 + (tx << 2) + jx;
      if (n >= N) continue;
      size_t jf = (size_t)m * N + n;
      float a = acc[i][jx];
      if (MODE == 0) {
        out[jf] = a;
      } else if (MODE == 1) {
        float pred = a + bias[n];
        float z = jax_normal_at((uint32_t)jf, half_n, key0, key1);
        out[jf] = Xin[jf] - pred + z * nscale;
      } else {
        float x = out[jf];
        float t = tanhf(x);
        float e = (E != nullptr) ? E[jf] : 0.0f;
        out[jf] = x + GAMMA_F * fmaf(a, 1.0f - t * t, -e);
      }
    }
  }
}

// ---------------- launch ----------------
extern "C" void kernel_launch(void* const* d_in, const int* in_sizes, int n_in,
                              void* d_out, int out_size, void* d_ws, size_t ws_size,
                              hipStream_t stream) {
  const float* obs = (const float*)d_in[0];
  const float* W1  = (const float*)d_in[1];  // 3072 x 4096
  const float* b1  = (const float*)d_in[2];
  const float* W2  = (const float*)d_in[3];  // 4096 x 4096
  const float* b2  = (const float*)d_in[4];
  const float* W3  = (const float*)d_in[5];  // 4096 x 2048
  const float* b3  = (const float*)d_in[6];
  const float* W4  = (const float*)d_in[7];  // 2048 x 1000
  const float* b4  = (const float*)d_in[8];

  float* out = (float*)d_out;  // xs[4]: 1024 x 1000

  // ---- workspace layout (bytes, 256-aligned) ----
  uint8_t* base = (uint8_t*)d_ws;
  size_t off = 0;
  auto alloc = [&](size_t bytes) -> size_t {
    size_t o = off;
    off = (off + bytes + 255) & ~(size_t)255;
    return o;
  };
  const size_t M = B_ROWS;
  size_t o_obsb = alloc(M * 3072 * 2);
  size_t o_t1 = alloc(M * 4096 * 2), o_t2 = alloc(M * 4096 * 2);
  size_t o_t3 = alloc(M * 2048 * 2), o_t4 = alloc(M * 1024 * 2);
  size_t o_es0 = alloc(M * 3072 * 2), o_es1 = alloc(M * 4096 * 2);
  size_t o_es2 = alloc(M * 4096 * 2), o_es3 = alloc(M * 2048 * 2);
  size_t o_x1b = alloc(M * 4096 * 2), o_x2b = alloc(M * 4096 * 2);
  size_t o_x3b = alloc(M * 2048 * 2);
  size_t o_W1b = alloc((size_t)3072 * 4096 * 2), o_W2b = alloc((size_t)4096 * 4096 * 2);
  size_t o_W3b = alloc((size_t)4096 * 2048 * 2), o_W4b = alloc((size_t)2048 * 1024 * 2);
  size_t o_W1T = alloc((size_t)4096 * 3072 * 2), o_W2T = alloc((size_t)4096 * 4096 * 2);
  size_t o_W3T = alloc((size_t)2048 * 4096 * 2), o_W4T = alloc((size_t)1024 * 2048 * 2);
  size_t o_xs1 = alloc(M * 4096 * 4), o_xs2 = alloc(M * 4096 * 4);
  size_t o_xs3 = alloc(M * 2048 * 4);
  size_t need = off;

  if (ws_size >= need) {
    // =================== bf16 MFMA path ===================
    short* obsb = (short*)(base + o_obsb);
    short* t1 = (short*)(base + o_t1); short* t2 = (short*)(base + o_t2);
    short* t3 = (short*)(base + o_t3); short* t4 = (short*)(base + o_t4);
    short* es0 = (short*)(base + o_es0); short* es1 = (short*)(base + o_es1);
    short* es2 = (short*)(base + o_es2); short* es3 = (short*)(base + o_es3);
    short* x1b = (short*)(base + o_x1b); short* x2b = (short*)(base + o_x2b);
    short* x3b = (short*)(base + o_x3b);
    short* W1b = (short*)(base + o_W1b); short* W2b = (short*)(base + o_W2b);
    short* W3b = (short*)(base + o_W3b); short* W4b = (short*)(base + o_W4b);
    short* W1T = (short*)(base + o_W1T); short* W2T = (short*)(base + o_W2T);
    short* W3T = (short*)(base + o_W3T); short* W4T = (short*)(base + o_W4T);
    float* xs1 = (float*)(base + o_xs1); float* xs2 = (float*)(base + o_xs2);
    float* xs3 = (float*)(base + o_xs3);

    // ---- prep ----
    {
      int n = (int)(M * 3072);
      cvt_k<<<(n + 255) / 256, 256, 0, stream>>>(obs, obsb, n);
    }
    cvt_pad_k<<<((3072 << 12) + 255) / 256, 256, 0, stream>>>(W1, W1b, 3072, 4096, 12);
    cvt_pad_k<<<((4096 << 12) + 255) / 256, 256, 0, stream>>>(W2, W2b, 4096, 4096, 12);
    cvt_pad_k<<<((4096 << 11) + 255) / 256, 256, 0, stream>>>(W3, W3b, 4096, 2048, 11);
    cvt_pad_k<<<((2048 << 10) + 255) / 256, 256, 0, stream>>>(W4, W4b, 2048, 1000, 10);
    transpose_k<<<dim3(4096 / 32, 3072 / 32), 256, 0, stream>>>(W1, W1T, 3072, 4096);
    transpose_k<<<dim3(4096 / 32, 4096 / 32), 256, 0, stream>>>(W2, W2T, 4096, 4096);
    transpose_k<<<dim3(2048 / 32, 4096 / 32), 256, 0, stream>>>(W3, W3T, 4096, 2048);
    transpose_k<<<dim3(32, 2048 / 32), 256, 0, stream>>>(W4, W4T, 2048, 1000);
    zero_pad_k<<<(1024 * 32) / 256, 256, 0, stream>>>(t4);

    // ---- init chain ----
    gemm0_k<<<dim3(32, 8), 256, 0, stream>>>(obsb, W1T, xs1, x1b, t1, 4096, 4096, 3072);
    gemm0_k<<<dim3(32, 8), 256, 0, stream>>>(x1b, W2T, xs2, x2b, t2, 4096, 4096, 4096);
    gemm0_k<<<dim3(16, 8), 256, 0, stream>>>(x2b, W3T, xs3, x3b, t3, 2048, 2048, 4096);
    gemm0_k<<<dim3(8, 8), 256, 0, stream>>>(x3b, W4T, out, nullptr, t4, 1024, 1000, 2048);

    // ---- phase params (constant parts) ----
    P1Args p1{};
    p1.A[0] = t1;  p1.A[1] = t2;  p1.A[2] = t3;  p1.A[3] = t4;
    p1.W[0] = W1b; p1.W[1] = W2b; p1.W[2] = W3b; p1.W[3] = W4b;
    p1.bias[0] = b1; p1.bias[1] = b2; p1.bias[2] = b3; p1.bias[3] = b4;
    p1.Xin[0] = obs; p1.Xin[1] = xs1; p1.Xin[2] = xs2; p1.Xin[3] = xs3;
    p1.Eout[0] = es0; p1.Eout[1] = es1; p1.Eout[2] = es2; p1.Eout[3] = es3;
    p1.N[0] = 3072; p1.N[1] = 4096; p1.N[2] = 4096; p1.N[3] = 2048;
    p1.K[0] = 4096; p1.K[1] = 4096; p1.K[2] = 2048; p1.K[3] = 1024;
    p1.cum[0] = 0; p1.cum[1] = 192; p1.cum[2] = 448; p1.cum[3] = 704; p1.cum[4] = 832;

    P2Args p2{};
    p2.A[0] = es0; p2.A[1] = es1; p2.A[2] = es2; p2.A[3] = es3;
    p2.W[0] = W1T; p2.W[1] = W2T; p2.W[2] = W3T; p2.W[3] = W4T;
    p2.E[0] = es1; p2.E[1] = es2; p2.E[2] = es3; p2.E[3] = nullptr;
    p2.Xs[0] = xs1; p2.Xs[1] = xs2; p2.Xs[2] = xs3; p2.Xs[3] = out;
    p2.T[0] = t1; p2.T[1] = t2; p2.T[2] = t3; p2.T[3] = t4;
    p2.N[0] = 4096; p2.N[1] = 4096; p2.N[2] = 2048; p2.N[3] = 1024;
    p2.Nlog[0] = 4096; p2.Nlog[1] = 4096; p2.Nlog[2] = 2048; p2.Nlog[3] = 1000;
    p2.K[0] = 3072; p2.K[1] = 4096; p2.K[2] = 4096; p2.K[3] = 2048;
    p2.cum[0] = 0; p2.cum[1] = 256; p2.cum[2] = 512; p2.cum[3] = 640; p2.cum[4] = 704;

    for (int i = 0; i < STEPS; ++i) {
      float scale = NOISE_SCALE_F * (1.0f - (float)i / (float)STEPS);
      uint32_t s0 = 0u, s1 = (uint32_t)i;
      tf2x32(0u, 42u, s0, s1);
      for (int li = 0; li < 4; ++li) {
        uint32_t a = 0u, bb = (uint32_t)li;
        tf2x32(s0, s1, a, bb);
        p1.key0[li] = a; p1.key1[li] = bb;
      }
      p1.nscale = scale;
      phase1_k<<<832, 256, 0, stream>>>(p1);
      phase2_k<<<704, 256, 0, stream>>>(p2);
    }
    return;
  }

  // =================== fp32 fallback (round-1 path) ===================
  float* ws = (float*)d_ws;
  float* xs1 = ws;
  float* xs2 = xs1 + (size_t)B_ROWS * 4096;
  float* xs3 = xs2 + (size_t)B_ROWS * 4096;
  float* es0 = xs3 + (size_t)B_ROWS * 2048;
  float* es1 = es0 + (size_t)B_ROWS * 3072;
  float* es2 = es1 + (size_t)B_ROWS * 4096;
  float* es3 = es2 + (size_t)B_ROWS * 4096;

  dim3 blk(256);
  auto grid_for = [](int N) { return dim3((N + 63) / 64, B_ROWS / 64); };

  gemm_k<0><<<grid_for(4096), blk, 0, stream>>>(obs, W1, nullptr, nullptr, nullptr, xs1,
                                                B_ROWS, 4096, 3072, 0u, 0u, 0.f);
  gemm_k<0><<<grid_for(4096), blk, 0, stream>>>(xs1, W2, nullptr, nullptr, nullptr, xs2,
                                                B_ROWS, 4096, 4096, 0u, 0u, 0.f);
  gemm_k<0><<<grid_for(2048), blk, 0, stream>>>(xs2, W3, nullptr, nullptr, nullptr, xs3,
                                                B_ROWS, 2048, 4096, 0u, 0u, 0.f);
  gemm_k<0><<<grid_for(1000), blk, 0, stream>>>(xs3, W4, nullptr, nullptr, nullptr, out,
                                                B_ROWS, 1000, 2048, 0u, 0u, 0.f);

  for (int i = 0; i < STEPS; ++i) {
    float scale = NOISE_SCALE_F * (1.0f - (float)i / (float)STEPS);
    uint32_t s0 = 0u, s1 = (uint32_t)i;
    tf2x32(0u, 42u, s0, s1);
    uint32_t kk[4][2];
    for (int li = 0; li < 4; ++li) {
      uint32_t a = 0u, bb = (uint32_t)li;
      tf2x32(s0, s1, a, bb);
      kk[li][0] = a; kk[li][1] = bb;
    }
    gemm_k<1><<<grid_for(3072), blk, 0, stream>>>(xs1, W1, b1, obs, nullptr, es0,
                                                  B_ROWS, 3072, 4096, kk[0][0], kk[0][1], scale);
    gemm_k<1><<<grid_for(4096), blk, 0, stream>>>(xs2, W2, b2, xs1, nullptr, es1,
                                                  B_ROWS, 4096, 4096, kk[1][0], kk[1][1], scale);
    gemm_k<1><<<grid_for(4096), blk, 0, stream>>>(xs3, W3, b3, xs2, nullptr, es2,
                                                  B_ROWS, 4096, 2048, kk[2][0], kk[2][1], scale);
    gemm_k<1><<<grid_for(2048), blk, 0, stream>>>(out, W4, b4, xs3, nullptr, es3,
                                                  B_ROWS, 2048, 1000, kk[3][0], kk[3][1], scale);
    gemm_k<2><<<grid_for(4096), blk, 0, stream>>>(es0, W1, nullptr, nullptr, es1, xs1,
                                                  B_ROWS, 4096, 3072, 0u, 0u, 0.f);
    gemm_k<2><<<grid_for(4096), blk, 0, stream>>>(es1, W2, nullptr, nullptr, es2, xs2,
                                                  B_ROWS, 4096, 4096, 0u, 0u, 0.f);
    gemm_k<2><<<grid_for(2048), blk, 0, stream>>>(es2, W3, nullptr, nullptr, es3, xs3,
                                                  B_ROWS, 2048, 4096, 0u, 0u, 0.f);
    gemm_k<2><<<grid_for(1000), blk, 0, stream>>>(es3, W4, nullptr, nullptr, nullptr, out,
                                                  B_ROWS, 1000, 2048, 0u, 0u, 0.f);
  }
}

// Round 3
// 25516.425 us; speedup vs baseline: 2.4662x; 2.4586x over previous
//
#include <hip/hip_runtime.h>
#include <cstdint>
#include <cmath>

// FCClassifier predictive-coding net, MI355X gfx950.
// Round 3: adaptive tiers by ws_size.
//   Tier A (~252MB): bf16 MFMA, dual-layout weights (all GEMMs fast NT).
//   Tier B (~172MB): bf16 MFMA, single-layout weights; phase2/init use NN
//                    B-staging ([k][n] LDS + quad-XOR chunk swizzle + u16 gather).
//   Tier C: fp32 vector fallback (round-1 proven, 62.9ms).
// Exact JAX threefry noise (validated round 1). fp32 state, fp32 MFMA accum.

#define B_ROWS 1024
#define STEPS 20
#define GAMMA_F 0.1f
#define NOISE_SCALE_F 0.034f

typedef float f32x4 __attribute__((ext_vector_type(4)));
typedef short sfrag __attribute__((ext_vector_type(8)));   // 8 bf16 in 4 VGPRs

// ---------------- threefry2x32 (matches jax._src.prng.threefry2x32) -------------
__host__ __device__ __forceinline__ uint32_t rotl32(uint32_t v, int r) {
  return (v << r) | (v >> (32 - r));
}
#define TF_ROUND(r) { x0 += x1; x1 = rotl32(x1, r); x1 ^= x0; }
__host__ __device__ __forceinline__ void tf2x32(uint32_t k0, uint32_t k1,
                                                uint32_t& x0, uint32_t& x1) {
  const uint32_t k2 = k0 ^ k1 ^ 0x1BD11BDAu;
  x0 += k0; x1 += k1;
  TF_ROUND(13) TF_ROUND(15) TF_ROUND(26) TF_ROUND(6)
  x0 += k1; x1 += k2 + 1u;
  TF_ROUND(17) TF_ROUND(29) TF_ROUND(16) TF_ROUND(24)
  x0 += k2; x1 += k0 + 2u;
  TF_ROUND(13) TF_ROUND(15) TF_ROUND(26) TF_ROUND(6)
  x0 += k0; x1 += k1 + 3u;
  TF_ROUND(17) TF_ROUND(29) TF_ROUND(16) TF_ROUND(24)
  x0 += k1; x1 += k2 + 4u;
  TF_ROUND(13) TF_ROUND(15) TF_ROUND(26) TF_ROUND(6)
  x0 += k2; x1 += k0 + 5u;
}

__device__ __forceinline__ float erfinv_f(float x) {
  float w = -log1pf(-x * x);
  float p;
  if (w < 5.0f) {
    w -= 2.5f;
    p = 2.81022636e-08f;
    p = fmaf(p, w, 3.43273939e-07f);
    p = fmaf(p, w, -3.5233877e-06f);
    p = fmaf(p, w, -4.39150654e-06f);
    p = fmaf(p, w, 0.00021858087f);
    p = fmaf(p, w, -0.00125372503f);
    p = fmaf(p, w, -0.00417768164f);
    p = fmaf(p, w, 0.246640727f);
    p = fmaf(p, w, 1.50140941f);
  } else {
    w = sqrtf(w) - 3.0f;
    p = -0.000200214257f;
    p = fmaf(p, w, 0.000100950558f);
    p = fmaf(p, w, 0.00134934322f);
    p = fmaf(p, w, -0.00367342844f);
    p = fmaf(p, w, 0.00573950773f);
    p = fmaf(p, w, -0.0076224613f);
    p = fmaf(p, w, 0.00943887047f);
    p = fmaf(p, w, 1.00167406f);
    p = fmaf(p, w, 2.83297682f);
  }
  return p * x;
}

__device__ __forceinline__ float jax_normal_at(uint32_t j, uint32_t half_n,
                                               uint32_t k0, uint32_t k1) {
  uint32_t blk, hi;
  if (j < half_n) { blk = j; hi = 0u; } else { blk = j - half_n; hi = 1u; }
  uint32_t x0 = blk, x1 = blk + half_n;
  tf2x32(k0, k1, x0, x1);
  uint32_t bits = hi ? x1 : x0;
  uint32_t fb = (bits >> 9) | 0x3f800000u;
  float f = __uint_as_float(fb) - 1.0f;
  const float LO = -0.99999994f;
  float u = fmaxf(LO, fmaf(f, 2.0f, LO));
  return 1.41421356237f * erfinv_f(u);
}

__device__ __forceinline__ short f2bf(float f) {
  uint32_t u = __float_as_uint(f);
  return (short)((u + 0x7fffu + ((u >> 16) & 1u)) >> 16);
}
__device__ __forceinline__ float b2f(short s) {
  return __uint_as_float(((uint32_t)(unsigned short)s) << 16);
}

// ---------------- MFMA core: C[128x128] at (m0,n0) ----------
// A: (M x K) bf16 row-major k-contiguous (stride K).
// BNN=false: B is (N x SB) row-major k-contiguous (SB==K) — fast NT path,
//   LDS [row][32k], 16B-chunk XOR swizzle chunk^=((row>>1)&3), ds_read_b128 frags.
// BNN=true:  B is (K x SB) row-major n-contiguous — NN path, LDS [k][128n]
//   rows of 256B with chunk placement p = chunk ^ ((k>>3)&3); fragment gather
//   8x ds_read_u16 (2-way bank aliasing only, free per m136).
template <bool BNN>
__device__ __forceinline__ void mfma_block(const short* __restrict__ Ag,
                                           const short* __restrict__ Bg,
                                           int K, int SB, int m0, int n0,
                                           short* As, short* Bs,
                                           f32x4 (&acc)[4][4]) {
  const int tid = threadIdx.x;
  const int ln = tid & 63, wv = tid >> 6;
  const int wm = wv >> 1, wn = wv & 1;
  const int c16 = ln & 15, quad = ln >> 4;
  const int rl = ln >> 2, cl = ln & 3;      // NT staging coords
  const int rb16 = ln >> 4, pb = ln & 15;   // BNN B staging coords

  for (int k0 = 0; k0 < K; k0 += 32) {
    __syncthreads();
#pragma unroll
    for (int half = 0; half < 2; ++half) {
      // A staging (always NT layout)
      {
        int Rb = wv * 32 + half * 16;
        int r = Rb + rl;
        int q = cl ^ ((r >> 1) & 3);
        const short* gA = Ag + (size_t)(m0 + r) * K + (k0 + q * 8);
        __builtin_amdgcn_global_load_lds(
            (const __attribute__((address_space(1))) void*)gA,
            (__attribute__((address_space(3))) void*)(As + Rb * 32), 16u, 0, 0);
      }
      if (!BNN) {
        int Rb = wv * 32 + half * 16;
        int r = Rb + rl;
        int q = cl ^ ((r >> 1) & 3);
        const short* gB = Bg + (size_t)(n0 + r) * SB + (k0 + q * 8);
        __builtin_amdgcn_global_load_lds(
            (const __attribute__((address_space(1))) void*)gB,
            (__attribute__((address_space(3))) void*)(Bs + Rb * 32), 16u, 0, 0);
      } else {
        int R = wv * 4 + half * 16;        // LDS k-row base for this issue
        int r2 = R + rb16;                 // k row 0..31
        int g = pb ^ ((r2 >> 3) & 3);      // global 16B chunk to fetch
        const short* gB = Bg + (size_t)(k0 + r2) * SB + (n0 + g * 8);
        __builtin_amdgcn_global_load_lds(
            (const __attribute__((address_space(1))) void*)gB,
            (__attribute__((address_space(3))) void*)(Bs + R * 128), 16u, 0, 0);
      }
    }
    __syncthreads();
    sfrag af[4], bfr[4];
#pragma unroll
    for (int t = 0; t < 4; ++t) {
      int ra = wm * 64 + t * 16 + c16;
      af[t] = *(const sfrag*)(As + ra * 32 + ((quad ^ ((ra >> 1) & 3)) * 8));
      if (!BNN) {
        int rbt = wn * 64 + t * 16 + c16;
        bfr[t] = *(const sfrag*)(Bs + rbt * 32 + ((quad ^ ((rbt >> 1) & 3)) * 8));
      } else {
        int n_l = wn * 64 + t * 16 + c16;
        int cb = (n_l >> 3) ^ quad;        // stored position of chunk n_l>>3 for k-rows quad*8..+7
        int off = n_l & 7;
        sfrag v;
#pragma unroll
        for (int j = 0; j < 8; ++j)
          v[j] = Bs[(quad * 8 + j) * 128 + cb * 8 + off];
        bfr[t] = v;
      }
    }
#pragma unroll
    for (int mt = 0; mt < 4; ++mt)
#pragma unroll
      for (int nt = 0; nt < 4; ++nt)
        acc[mt][nt] = __builtin_amdgcn_mfma_f32_16x16x32_bf16(
            af[mt], bfr[nt], acc[mt][nt], 0, 0, 0);
  }
}

// ---------------- fused phase kernels ----------------
struct P1Args {
  const short *A[4], *W[4];
  const float *bias[4], *Xin[4];
  short *Eout[4];
  int N[4], K[4], SB[4], cum[5];
  uint32_t key0[4], key1[4];
  float nscale;
};

__global__ __launch_bounds__(256) void phase1_k(P1Args p) {
  int b = blockIdx.x;
  int li = (b >= p.cum[2]) ? ((b >= p.cum[3]) ? 3 : 2) : ((b >= p.cum[1]) ? 1 : 0);
  int local = b - p.cum[li];
  int m0 = (local & 7) << 7, n0 = (local >> 3) << 7;
  const int N = p.N[li], K = p.K[li], SB = p.SB[li];

  __shared__ alignas(16) short As[128 * 32];
  __shared__ alignas(16) short Bs[128 * 32];
  f32x4 acc[4][4];
#pragma unroll
  for (int i = 0; i < 4; ++i)
#pragma unroll
    for (int j = 0; j < 4; ++j) acc[i][j] = (f32x4){0.f, 0.f, 0.f, 0.f};

  mfma_block<false>(p.A[li], p.W[li], K, SB, m0, n0, As, Bs, acc);

  const int tid = threadIdx.x, ln = tid & 63, wv = tid >> 6;
  const int wm = wv >> 1, wn = wv & 1, c16 = ln & 15, quad = ln >> 4;
  const float* Xin = p.Xin[li];
  const float* bias = p.bias[li];
  short* Eo = p.Eout[li];
  const uint32_t halfn = (uint32_t)(((size_t)B_ROWS * (size_t)N) >> 1);
  const uint32_t K0 = p.key0[li], K1 = p.key1[li];
  const float ns = p.nscale;
#pragma unroll
  for (int mt = 0; mt < 4; ++mt)
#pragma unroll
    for (int nt = 0; nt < 4; ++nt)
#pragma unroll
      for (int rg = 0; rg < 4; ++rg) {
        int m = m0 + wm * 64 + mt * 16 + quad * 4 + rg;
        int n = n0 + wn * 64 + nt * 16 + c16;
        size_t jf = (size_t)m * N + n;
        float pred = acc[mt][nt][rg] + bias[n];
        float z = jax_normal_at((uint32_t)jf, halfn, K0, K1);
        Eo[jf] = f2bf(Xin[jf] - pred + z * ns);
      }
}

struct P2Args {
  const short *A[4], *W[4], *E[4];
  float *Xs[4];
  short *T[4];
  int N[4], Nlog[4], K[4], SB[4], cum[5];
};

template <bool BNN>
__global__ __launch_bounds__(256) void phase2_k(P2Args p) {
  int b = blockIdx.x;
  int li = (b >= p.cum[2]) ? ((b >= p.cum[3]) ? 3 : 2) : ((b >= p.cum[1]) ? 1 : 0);
  int local = b - p.cum[li];
  int m0 = (local & 7) << 7, n0 = (local >> 3) << 7;
  const int N = p.N[li], Nlog = p.Nlog[li], K = p.K[li], SB = p.SB[li];

  __shared__ alignas(16) short As[128 * 32];
  __shared__ alignas(16) short Bs[128 * 32];
  f32x4 acc[4][4];
#pragma unroll
  for (int i = 0; i < 4; ++i)
#pragma unroll
    for (int j = 0; j < 4; ++j) acc[i][j] = (f32x4){0.f, 0.f, 0.f, 0.f};

  mfma_block<BNN>(p.A[li], p.W[li], K, SB, m0, n0, As, Bs, acc);

  const int tid = threadIdx.x, ln = tid & 63, wv = tid >> 6;
  const int wm = wv >> 1, wn = wv & 1, c16 = ln & 15, quad = ln >> 4;
  const short* Ep = p.E[li];
  float* Xs = p.Xs[li];
  short* T = p.T[li];
#pragma unroll
  for (int mt = 0; mt < 4; ++mt)
#pragma unroll
    for (int nt = 0; nt < 4; ++nt)
#pragma unroll
      for (int rg = 0; rg < 4; ++rg) {
        int m = m0 + wm * 64 + mt * 16 + quad * 4 + rg;
        int n = n0 + wn * 64 + nt * 16 + c16;
        if (n >= Nlog) continue;
        size_t jfX = (size_t)m * Nlog + n;
        float x = Xs[jfX];
        float t = tanhf(x);
        float e = Ep ? b2f(Ep[jfX]) : 0.f;
        float xn = x + GAMMA_F * fmaf(acc[mt][nt][rg], 1.0f - t * t, -e);
        Xs[jfX] = xn;
        T[(size_t)m * N + n] = f2bf(tanhf(xn));
      }
}

// init: C = A @ W; writes xs fp32, x bf16 (optional), tanh bf16
template <bool BNN>
__global__ __launch_bounds__(256) void gemm0_k(const short* __restrict__ A,
                                               const short* __restrict__ W,
                                               float* __restrict__ Xs,
                                               short* __restrict__ Xb,
                                               short* __restrict__ T,
                                               int Ngrid, int Nlog, int K, int SB) {
  int m0 = blockIdx.y << 7, n0 = blockIdx.x << 7;
  __shared__ alignas(16) short As[128 * 32];
  __shared__ alignas(16) short Bs[128 * 32];
  f32x4 acc[4][4];
#pragma unroll
  for (int i = 0; i < 4; ++i)
#pragma unroll
    for (int j = 0; j < 4; ++j) acc[i][j] = (f32x4){0.f, 0.f, 0.f, 0.f};

  mfma_block<BNN>(A, W, K, SB, m0, n0, As, Bs, acc);

  const int tid = threadIdx.x, ln = tid & 63, wv = tid >> 6;
  const int wm = wv >> 1, wn = wv & 1, c16 = ln & 15, quad = ln >> 4;
#pragma unroll
  for (int mt = 0; mt < 4; ++mt)
#pragma unroll
    for (int nt = 0; nt < 4; ++nt)
#pragma unroll
      for (int rg = 0; rg < 4; ++rg) {
        int m = m0 + wm * 64 + mt * 16 + quad * 4 + rg;
        int n = n0 + wn * 64 + nt * 16 + c16;
        if (n >= Nlog) continue;
        size_t jf = (size_t)m * Nlog + n;
        float x = acc[mt][nt][rg];
        Xs[jf] = x;
        if (Xb) Xb[jf] = f2bf(x);
        T[(size_t)m * Ngrid + n] = f2bf(tanhf(x));
      }
}

// ---------------- prep kernels ----------------
__global__ void cvt_k(const float* __restrict__ s, short* __restrict__ d, int n) {
  int i = blockIdx.x * blockDim.x + threadIdx.x;
  if (i < n) d[i] = f2bf(s[i]);
}

// dst (R x 2^sh) bf16 from src (R x Cs) fp32, zero pad cols >= Cs
__global__ void cvt_pad_k(const float* __restrict__ s, short* __restrict__ d,
                          int R, int Cs, int sh) {
  int i = blockIdx.x * blockDim.x + threadIdx.x;
  int total = R << sh;
  if (i >= total) return;
  int r = i >> sh, c = i & ((1 << sh) - 1);
  d[i] = (c < Cs) ? f2bf(s[(size_t)r * Cs + c]) : (short)0;
}

// dst[c*R + r] = bf16(src[r*C + c]); R multiple of 32; guard c < C
__global__ void transpose_k(const float* __restrict__ s, short* __restrict__ d,
                            int R, int C) {
  __shared__ float tile[32][33];
  int cb = blockIdx.x * 32, rb = blockIdx.y * 32;
  int tx = threadIdx.x & 31, ty = threadIdx.x >> 5;  // 256 threads
#pragma unroll
  for (int i = 0; i < 4; ++i) {
    int r = rb + ty + i * 8, c = cb + tx;
    if (c < C) tile[ty + i * 8][tx] = s[(size_t)r * C + c];
  }
  __syncthreads();
#pragma unroll
  for (int i = 0; i < 4; ++i) {
    int rr = rb + tx, cc = cb + ty + i * 8;
    if (cc < C) d[(size_t)cc * R + rr] = f2bf(tile[tx][ty + i * 8]);
  }
}

// zero t4 pad columns [1000,1024) for 1024 rows
__global__ void zero_pad_k(short* __restrict__ t4) {
  int i = blockIdx.x * blockDim.x + threadIdx.x;
  int r = i >> 5, c = i & 31;
  if (r < 1024 && c < 24) t4[(size_t)r * 1024 + 1000 + c] = 0;
}

// ================= fp32 fallback (round-1, proven) =================
template <int MODE>
__global__ __launch_bounds__(256)
void gemm_k(const float* __restrict__ A, const float* __restrict__ W,
            const float* __restrict__ bias, const float* __restrict__ Xin,
            const float* __restrict__ E, float* __restrict__ out,
            int M, int N, int K,
            uint32_t key0, uint32_t key1, float nscale) {
  __shared__ float As[16][68];
  __shared__ float Bs[16][68];
  const int tid = threadIdx.x;
  const int m0 = blockIdx.y * 64;
  const int n0 = blockIdx.x * 64;
  const int tx = tid & 15;
  const int ty = tid >> 4;
  float acc[4][4] = {};
  for (int k0 = 0; k0 < K; k0 += 16) {
    {
      int m_l = tid >> 2;
      int k_l = (tid & 3) << 2;
      int gk = k0 + k_l;
      float4 v = make_float4(0.f, 0.f, 0.f, 0.f);
      if (gk < K) v = *reinterpret_cast<const float4*>(A + (size_t)(m0 + m_l) * K + gk);
      if (MODE == 1) { v.x = tanhf(v.x); v.y = tanhf(v.y); v.z = tanhf(v.z); v.w = tanhf(v.w); }
      As[k_l + 0][m_l] = v.x; As[k_l + 1][m_l] = v.y;
      As[k_l + 2][m_l] = v.z; As[k_l + 3][m_l] = v.w;
    }
    if (MODE == 1) {
      int n_l = tid >> 2;
      int k_l = (tid & 3) << 2;
      int gn = n0 + n_l, gk = k0 + k_l;
      float4 v = make_float4(0.f, 0.f, 0.f, 0.f);
      if (gn < N && gk < K) v = *reinterpret_cast<const float4*>(W + (size_t)gn * K + gk);
      Bs[k_l + 0][n_l] = v.x; Bs[k_l + 1][n_l] = v.y;
      Bs[k_l + 2][n_l] = v.z; Bs[k_l + 3][n_l] = v.w;
    } else {
      int k_l = tid >> 4;
      int n_l = (tid & 15) << 2;
      int gk = k0 + k_l, gn = n0 + n_l;
      float4 v = make_float4(0.f, 0.f, 0.f, 0.f);
      if (gk < K && gn < N) v = *reinterpret_cast<const float4*>(W + (size_t)gk * N + gn);
      *reinterpret_cast<float4*>(&Bs[k_l][n_l]) = v;
    }
    __syncthreads();
#pragma unroll
    for (int kk = 0; kk < 16; ++kk) {
      float4 a = *reinterpret_cast<const float4*>(&As[kk][ty << 2]);
      float4 b = *reinterpret_cast<const float4*>(&Bs[kk][tx << 2]);
      acc[0][0] = fmaf(a.x, b.x, acc[0][0]); acc[0][1] = fmaf(a.x, b.y, acc[0][1]);
      acc[0][2] = fmaf(a.x, b.z, acc[0][2]); acc[0][3] = fmaf(a.x, b.w, acc[0][3]);
      acc[1][0] = fmaf(a.y, b.x, acc[1][0]); acc[1][1] = fmaf(a.y, b.y, acc[1][1]);
      acc[1][2] = fmaf(a.y, b.z, acc[1][2]); acc[1][3] = fmaf(a.y, b.w, acc[1][3]);
      acc[2][0] = fmaf(a.z, b.x, acc[2][0]); acc[2][1] = fmaf(a.z, b.y, acc[2][1]);
      acc[2][2] = fmaf(a.z, b.z, acc[2][2]); acc[2][3] = fmaf(a.z, b.w, acc[2][3]);
      acc[3][0] = fmaf(a.w, b.x, acc[3][0]); acc[3][1] = fmaf(a.w, b.y, acc[3][1]);
      acc[3][2] = fmaf(a.w, b.z, acc[3][2]); acc[3][3] = fmaf(a.w, b.w, acc[3][3]);
    }
    __syncthreads();
  }
  const uint32_t half_n = (uint32_t)(((size_t)M * N) >> 1);
#pragma unroll
  for (int i = 0; i < 4; ++i) {
    int m = m0 + (ty << 2) + i;
#pragma unroll
    for (int jx = 0; jx < 4; ++jx) {
      int n = n0 + (tx << 2) + jx;
      if (n >= N) continue;
      size_t jf = (size_t)m * N + n;
      float a = acc[i][jx];
      if (MODE == 0) {
        out[jf] = a;
      } else if (MODE == 1) {
        float pred = a + bias[n];
        float z = jax_normal_at((uint32_t)jf, half_n, key0, key1);
        out[jf] = Xin[jf] - pred + z * nscale;
      } else {
        float x = out[jf];
        float t = tanhf(x);
        float e = (E != nullptr) ? E[jf] : 0.0f;
        out[jf] = x + GAMMA_F * fmaf(a, 1.0f - t * t, -e);
      }
    }
  }
}

// ---------------- launch ----------------
extern "C" void kernel_launch(void* const* d_in, const int* in_sizes, int n_in,
                              void* d_out, int out_size, void* d_ws, size_t ws_size,
                              hipStream_t stream) {
  const float* obs = (const float*)d_in[0];
  const float* W1  = (const float*)d_in[1];  // 3072 x 4096
  const float* b1  = (const float*)d_in[2];
  const float* W2  = (const float*)d_in[3];  // 4096 x 4096
  const float* b2  = (const float*)d_in[4];
  const float* W3  = (const float*)d_in[5];  // 4096 x 2048
  const float* b3  = (const float*)d_in[6];
  const float* W4  = (const float*)d_in[7];  // 2048 x 1000
  const float* b4  = (const float*)d_in[8];

  float* out = (float*)d_out;  // xs[4]: 1024 x 1000

  uint8_t* base = (uint8_t*)d_ws;
  size_t off = 0;
  auto alloc = [&](size_t bytes) -> size_t {
    size_t o = off;
    off = (off + bytes + 255) & ~(size_t)255;
    return o;
  };
  const size_t M = B_ROWS;
  // shared by tiers A and B:
  size_t o_t1 = alloc(M * 4096 * 2), o_t2 = alloc(M * 4096 * 2);
  size_t o_t3 = alloc(M * 2048 * 2), o_t4 = alloc(M * 1024 * 2);
  size_t o_es0 = alloc(M * 3072 * 2), o_es1 = alloc(M * 4096 * 2);
  size_t o_es2 = alloc(M * 4096 * 2), o_es3 = alloc(M * 2048 * 2);
  size_t o_W1b = alloc((size_t)3072 * 4096 * 2), o_W2b = alloc((size_t)4096 * 4096 * 2);
  size_t o_W3b = alloc((size_t)4096 * 2048 * 2), o_W4b = alloc((size_t)2048 * 1024 * 2);
  size_t o_xs1 = alloc(M * 4096 * 4), o_xs2 = alloc(M * 4096 * 4);
  size_t o_xs3 = alloc(M * 2048 * 4);
  size_t need_B = off;
  // tier A only:
  size_t o_W1T = alloc((size_t)4096 * 3072 * 2), o_W2T = alloc((size_t)4096 * 4096 * 2);
  size_t o_W3T = alloc((size_t)2048 * 4096 * 2), o_W4T = alloc((size_t)1024 * 2048 * 2);
  size_t need_A = off;

  if (ws_size >= need_B) {
    const bool tierA = (ws_size >= need_A);
    short* t1 = (short*)(base + o_t1); short* t2 = (short*)(base + o_t2);
    short* t3 = (short*)(base + o_t3); short* t4 = (short*)(base + o_t4);
    short* es0 = (short*)(base + o_es0); short* es1 = (short*)(base + o_es1);
    short* es2 = (short*)(base + o_es2); short* es3 = (short*)(base + o_es3);
    short* W1b = (short*)(base + o_W1b); short* W2b = (short*)(base + o_W2b);
    short* W3b = (short*)(base + o_W3b); short* W4b = (short*)(base + o_W4b);
    float* xs1 = (float*)(base + o_xs1); float* xs2 = (float*)(base + o_xs2);
    float* xs3 = (float*)(base + o_xs3);
    short* W1T = (short*)(base + o_W1T); short* W2T = (short*)(base + o_W2T);
    short* W3T = (short*)(base + o_W3T); short* W4T = (short*)(base + o_W4T);

    // init-chain bf16-x scratch reuses es buffers (overwritten in step loop)
    short* obsb = es0;   // 1024x3072
    short* x1b = es1;    // 1024x4096
    short* x2b = es2;    // 1024x4096
    short* x3b = es3;    // 1024x2048

    // ---- prep ----
    {
      int n = (int)(M * 3072);
      cvt_k<<<(n + 255) / 256, 256, 0, stream>>>(obs, obsb, n);
    }
    cvt_pad_k<<<((3072 << 12) + 255) / 256, 256, 0, stream>>>(W1, W1b, 3072, 4096, 12);
    cvt_pad_k<<<((4096 << 12) + 255) / 256, 256, 0, stream>>>(W2, W2b, 4096, 4096, 12);
    cvt_pad_k<<<((4096 << 11) + 255) / 256, 256, 0, stream>>>(W3, W3b, 4096, 2048, 11);
    cvt_pad_k<<<((2048 << 10) + 255) / 256, 256, 0, stream>>>(W4, W4b, 2048, 1000, 10);
    if (tierA) {
      transpose_k<<<dim3(4096 / 32, 3072 / 32), 256, 0, stream>>>(W1, W1T, 3072, 4096);
      transpose_k<<<dim3(4096 / 32, 4096 / 32), 256, 0, stream>>>(W2, W2T, 4096, 4096);
      transpose_k<<<dim3(2048 / 32, 4096 / 32), 256, 0, stream>>>(W3, W3T, 4096, 2048);
      transpose_k<<<dim3(32, 2048 / 32), 256, 0, stream>>>(W4, W4T, 2048, 1000);
    }
    zero_pad_k<<<(1024 * 32) / 256, 256, 0, stream>>>(t4);

    // ---- init chain: xs[l+1] = xs[l] @ W_{l+1} (linear, no tanh) ----
    if (tierA) {
      gemm0_k<false><<<dim3(32, 8), 256, 0, stream>>>(obsb, W1T, xs1, x1b, t1, 4096, 4096, 3072, 3072);
      gemm0_k<false><<<dim3(32, 8), 256, 0, stream>>>(x1b, W2T, xs2, x2b, t2, 4096, 4096, 4096, 4096);
      gemm0_k<false><<<dim3(16, 8), 256, 0, stream>>>(x2b, W3T, xs3, x3b, t3, 2048, 2048, 4096, 4096);
      gemm0_k<false><<<dim3(8, 8), 256, 0, stream>>>(x3b, W4T, out, nullptr, t4, 1024, 1000, 2048, 2048);
    } else {
      gemm0_k<true><<<dim3(32, 8), 256, 0, stream>>>(obsb, W1b, xs1, x1b, t1, 4096, 4096, 3072, 4096);
      gemm0_k<true><<<dim3(32, 8), 256, 0, stream>>>(x1b, W2b, xs2, x2b, t2, 4096, 4096, 4096, 4096);
      gemm0_k<true><<<dim3(16, 8), 256, 0, stream>>>(x2b, W3b, xs3, x3b, t3, 2048, 2048, 4096, 2048);
      gemm0_k<true><<<dim3(8, 8), 256, 0, stream>>>(x3b, W4b, out, nullptr, t4, 1024, 1000, 2048, 1024);
    }

    // ---- phase arg blocks ----
    P1Args p1{};
    p1.A[0] = t1;  p1.A[1] = t2;  p1.A[2] = t3;  p1.A[3] = t4;
    p1.W[0] = W1b; p1.W[1] = W2b; p1.W[2] = W3b; p1.W[3] = W4b;
    p1.bias[0] = b1; p1.bias[1] = b2; p1.bias[2] = b3; p1.bias[3] = b4;
    p1.Xin[0] = obs; p1.Xin[1] = xs1; p1.Xin[2] = xs2; p1.Xin[3] = xs3;
    p1.Eout[0] = es0; p1.Eout[1] = es1; p1.Eout[2] = es2; p1.Eout[3] = es3;
    p1.N[0] = 3072; p1.N[1] = 4096; p1.N[2] = 4096; p1.N[3] = 2048;
    p1.K[0] = 4096; p1.K[1] = 4096; p1.K[2] = 2048; p1.K[3] = 1024;
    p1.SB[0] = 4096; p1.SB[1] = 4096; p1.SB[2] = 2048; p1.SB[3] = 1024;
    p1.cum[0] = 0; p1.cum[1] = 192; p1.cum[2] = 448; p1.cum[3] = 704; p1.cum[4] = 832;

    P2Args p2{};
    p2.A[0] = es0; p2.A[1] = es1; p2.A[2] = es2; p2.A[3] = es3;
    if (tierA) {
      p2.W[0] = W1T; p2.W[1] = W2T; p2.W[2] = W3T; p2.W[3] = W4T;
      p2.SB[0] = 3072; p2.SB[1] = 4096; p2.SB[2] = 4096; p2.SB[3] = 2048;  // = K
    } else {
      p2.W[0] = W1b; p2.W[1] = W2b; p2.W[2] = W3b; p2.W[3] = W4b;
      p2.SB[0] = 4096; p2.SB[1] = 4096; p2.SB[2] = 2048; p2.SB[3] = 1024;  // = N row width
    }
    p2.E[0] = es1; p2.E[1] = es2; p2.E[2] = es3; p2.E[3] = nullptr;
    p2.Xs[0] = xs1; p2.Xs[1] = xs2; p2.Xs[2] = xs3; p2.Xs[3] = out;
    p2.T[0] = t1; p2.T[1] = t2; p2.T[2] = t3; p2.T[3] = t4;
    p2.N[0] = 4096; p2.N[1] = 4096; p2.N[2] = 2048; p2.N[3] = 1024;
    p2.Nlog[0] = 4096; p2.Nlog[1] = 4096; p2.Nlog[2] = 2048; p2.Nlog[3] = 1000;
    p2.K[0] = 3072; p2.K[1] = 4096; p2.K[2] = 4096; p2.K[3] = 2048;
    p2.cum[0] = 0; p2.cum[1] = 256; p2.cum[2] = 512; p2.cum[3] = 640; p2.cum[4] = 704;

    for (int i = 0; i < STEPS; ++i) {
      float scale = NOISE_SCALE_F * (1.0f - (float)i / (float)STEPS);
      uint32_t s0 = 0u, s1 = (uint32_t)i;
      tf2x32(0u, 42u, s0, s1);
      for (int li = 0; li < 4; ++li) {
        uint32_t a = 0u, bb = (uint32_t)li;
        tf2x32(s0, s1, a, bb);
        p1.key0[li] = a; p1.key1[li] = bb;
      }
      p1.nscale = scale;
      phase1_k<<<832, 256, 0, stream>>>(p1);
      if (tierA) phase2_k<false><<<704, 256, 0, stream>>>(p2);
      else       phase2_k<true><<<704, 256, 0, stream>>>(p2);
    }
    return;
  }

  // =================== fp32 fallback (round-1 path, ~96.5MB) ===================
  float* ws = (float*)d_ws;
  float* xs1 = ws;
  float* xs2 = xs1 + (size_t)B_ROWS * 4096;
  float* xs3 = xs2 + (size_t)B_ROWS * 4096;
  float* es0 = xs3 + (size_t)B_ROWS * 2048;
  float* es1 = es0 + (size_t)B_ROWS * 3072;
  float* es2 = es1 + (size_t)B_ROWS * 4096;
  float* es3 = es2 + (size_t)B_ROWS * 4096;

  dim3 blk(256);
  auto grid_for = [](int N) { return dim3((N + 63) / 64, B_ROWS / 64); };

  gemm_k<0><<<grid_for(4096), blk, 0, stream>>>(obs, W1, nullptr, nullptr, nullptr, xs1,
                                                B_ROWS, 4096, 3072, 0u, 0u, 0.f);
  gemm_k<0><<<grid_for(4096), blk, 0, stream>>>(xs1, W2, nullptr, nullptr, nullptr, xs2,
                                                B_ROWS, 4096, 4096, 0u, 0u, 0.f);
  gemm_k<0><<<grid_for(2048), blk, 0, stream>>>(xs2, W3, nullptr, nullptr, nullptr, xs3,
                                                B_ROWS, 2048, 4096, 0u, 0u, 0.f);
  gemm_k<0><<<grid_for(1000), blk, 0, stream>>>(xs3, W4, nullptr, nullptr, nullptr, out,
                                                B_ROWS, 1000, 2048, 0u, 0u, 0.f);

  for (int i = 0; i < STEPS; ++i) {
    float scale = NOISE_SCALE_F * (1.0f - (float)i / (float)STEPS);
    uint32_t s0 = 0u, s1 = (uint32_t)i;
    tf2x32(0u, 42u, s0, s1);
    uint32_t kk[4][2];
    for (int li = 0; li < 4; ++li) {
      uint32_t a = 0u, bb = (uint32_t)li;
      tf2x32(s0, s1, a, bb);
      kk[li][0] = a; kk[li][1] = bb;
    }
    gemm_k<1><<<grid_for(3072), blk, 0, stream>>>(xs1, W1, b1, obs, nullptr, es0,
                                                  B_ROWS, 3072, 4096, kk[0][0], kk[0][1], scale);
    gemm_k<1><<<grid_for(4096), blk, 0, stream>>>(xs2, W2, b2, xs1, nullptr, es1,
                                                  B_ROWS, 4096, 4096, kk[1][0], kk[1][1], scale);
    gemm_k<1><<<grid_for(4096), blk, 0, stream>>>(xs3, W3, b3, xs2, nullptr, es2,
                                                  B_ROWS, 4096, 2048, kk[2][0], kk[2][1], scale);
    gemm_k<1><<<grid_for(2048), blk, 0, stream>>>(out, W4, b4, xs3, nullptr, es3,
                                                  B_ROWS, 2048, 1000, kk[3][0], kk[3][1], scale);
    gemm_k<2><<<grid_for(4096), blk, 0, stream>>>(es0, W1, nullptr, nullptr, es1, xs1,
                                                  B_ROWS, 4096, 3072, 0u, 0u, 0.f);
    gemm_k<2><<<grid_for(4096), blk, 0, stream>>>(es1, W2, nullptr, nullptr, es2, xs2,
                                                  B_ROWS, 4096, 4096, 0u, 0u, 0.f);
    gemm_k<2><<<grid_for(2048), blk, 0, stream>>>(es2, W3, nullptr, nullptr, es3, xs3,
                                                  B_ROWS, 2048, 4096, 0u, 0u, 0.f);
    gemm_k<2><<<grid_for(1000), blk, 0, stream>>>(es3, W4, nullptr, nullptr, nullptr, out,
                                                  B_ROWS, 1000, 2048, 0u, 0u, 0.f);
  }
}

// Round 4
// 7271.616 us; speedup vs baseline: 8.6540x; 3.5090x over previous
//
#include <hip/hip_runtime.h>
#include <cstdint>
#include <cmath>

// FCClassifier predictive-coding net, MI355X gfx950.
// Round 4: fix phase1 scratch-traffic pathology (4.4GB HBM writes/dispatch):
//   - inline fast log in erfinv (no OCML log1pf call -> no per-call VGPR spills)
//   - no runtime-indexed aggregates in phase kernels (named fields + uniform selects)
// Tiers: A (~252MB dual-layout bf16) / B (~172MB single-layout) / C fp32 fallback.

#define B_ROWS 1024
#define STEPS 20
#define GAMMA_F 0.1f
#define NOISE_SCALE_F 0.034f

typedef float f32x4 __attribute__((ext_vector_type(4)));
typedef short sfrag __attribute__((ext_vector_type(8)));   // 8 bf16 in 4 VGPRs

// ---------------- threefry2x32 (matches jax._src.prng.threefry2x32) -------------
__host__ __device__ __forceinline__ uint32_t rotl32(uint32_t v, int r) {
  return (v << r) | (v >> (32 - r));
}
#define TF_ROUND(r) { x0 += x1; x1 = rotl32(x1, r); x1 ^= x0; }
__host__ __device__ __forceinline__ void tf2x32(uint32_t k0, uint32_t k1,
                                                uint32_t& x0, uint32_t& x1) {
  const uint32_t k2 = k0 ^ k1 ^ 0x1BD11BDAu;
  x0 += k0; x1 += k1;
  TF_ROUND(13) TF_ROUND(15) TF_ROUND(26) TF_ROUND(6)
  x0 += k1; x1 += k2 + 1u;
  TF_ROUND(17) TF_ROUND(29) TF_ROUND(16) TF_ROUND(24)
  x0 += k2; x1 += k0 + 2u;
  TF_ROUND(13) TF_ROUND(15) TF_ROUND(26) TF_ROUND(6)
  x0 += k0; x1 += k1 + 3u;
  TF_ROUND(17) TF_ROUND(29) TF_ROUND(16) TF_ROUND(24)
  x0 += k1; x1 += k2 + 4u;
  TF_ROUND(13) TF_ROUND(15) TF_ROUND(26) TF_ROUND(6)
  x0 += k2; x1 += k0 + 5u;
}

// XLA f32 ErfInv (Giles), with fully-inline fast log (v_log_f32):
// w = -log(1-x^2). Noise path needs ~1e-3 abs accuracy; __logf is plenty.
__device__ __forceinline__ float erfinv_f(float x) {
  float w = -__logf(fmaf(x, -x, 1.0f));
  float p;
  if (w < 5.0f) {
    w -= 2.5f;
    p = 2.81022636e-08f;
    p = fmaf(p, w, 3.43273939e-07f);
    p = fmaf(p, w, -3.5233877e-06f);
    p = fmaf(p, w, -4.39150654e-06f);
    p = fmaf(p, w, 0.00021858087f);
    p = fmaf(p, w, -0.00125372503f);
    p = fmaf(p, w, -0.00417768164f);
    p = fmaf(p, w, 0.246640727f);
    p = fmaf(p, w, 1.50140941f);
  } else {
    w = sqrtf(w) - 3.0f;
    p = -0.000200214257f;
    p = fmaf(p, w, 0.000100950558f);
    p = fmaf(p, w, 0.00134934322f);
    p = fmaf(p, w, -0.00367342844f);
    p = fmaf(p, w, 0.00573950773f);
    p = fmaf(p, w, -0.0076224613f);
    p = fmaf(p, w, 0.00943887047f);
    p = fmaf(p, w, 1.00167406f);
    p = fmaf(p, w, 2.83297682f);
  }
  return p * x;
}

__device__ __forceinline__ float jax_normal_at(uint32_t j, uint32_t half_n,
                                               uint32_t k0, uint32_t k1) {
  uint32_t blk, hi;
  if (j < half_n) { blk = j; hi = 0u; } else { blk = j - half_n; hi = 1u; }
  uint32_t x0 = blk, x1 = blk + half_n;
  tf2x32(k0, k1, x0, x1);
  uint32_t bits = hi ? x1 : x0;
  uint32_t fb = (bits >> 9) | 0x3f800000u;
  float f = __uint_as_float(fb) - 1.0f;
  const float LO = -0.99999994f;
  float u = fmaxf(LO, fmaf(f, 2.0f, LO));
  return 1.41421356237f * erfinv_f(u);
}

__device__ __forceinline__ short f2bf(float f) {
  uint32_t u = __float_as_uint(f);
  return (short)((u + 0x7fffu + ((u >> 16) & 1u)) >> 16);
}
__device__ __forceinline__ float b2f(short s) {
  return __uint_as_float(((uint32_t)(unsigned short)s) << 16);
}

// ---------------- MFMA core: C[128x128] at (m0,n0) ----------
template <bool BNN>
__device__ __forceinline__ void mfma_block(const short* __restrict__ Ag,
                                           const short* __restrict__ Bg,
                                           int K, int SB, int m0, int n0,
                                           short* As, short* Bs,
                                           f32x4 (&acc)[4][4]) {
  const int tid = threadIdx.x;
  const int ln = tid & 63, wv = tid >> 6;
  const int wm = wv >> 1, wn = wv & 1;
  const int c16 = ln & 15, quad = ln >> 4;
  const int rl = ln >> 2, cl = ln & 3;
  const int rb16 = ln >> 4, pb = ln & 15;

  for (int k0 = 0; k0 < K; k0 += 32) {
    __syncthreads();
#pragma unroll
    for (int half = 0; half < 2; ++half) {
      {
        int Rb = wv * 32 + half * 16;
        int r = Rb + rl;
        int q = cl ^ ((r >> 1) & 3);
        const short* gA = Ag + (size_t)(m0 + r) * K + (k0 + q * 8);
        __builtin_amdgcn_global_load_lds(
            (const __attribute__((address_space(1))) void*)gA,
            (__attribute__((address_space(3))) void*)(As + Rb * 32), 16u, 0, 0);
      }
      if (!BNN) {
        int Rb = wv * 32 + half * 16;
        int r = Rb + rl;
        int q = cl ^ ((r >> 1) & 3);
        const short* gB = Bg + (size_t)(n0 + r) * SB + (k0 + q * 8);
        __builtin_amdgcn_global_load_lds(
            (const __attribute__((address_space(1))) void*)gB,
            (__attribute__((address_space(3))) void*)(Bs + Rb * 32), 16u, 0, 0);
      } else {
        int R = wv * 4 + half * 16;
        int r2 = R + rb16;
        int g = pb ^ ((r2 >> 3) & 3);
        const short* gB = Bg + (size_t)(k0 + r2) * SB + (n0 + g * 8);
        __builtin_amdgcn_global_load_lds(
            (const __attribute__((address_space(1))) void*)gB,
            (__attribute__((address_space(3))) void*)(Bs + R * 128), 16u, 0, 0);
      }
    }
    __syncthreads();
    sfrag af[4], bfr[4];
#pragma unroll
    for (int t = 0; t < 4; ++t) {
      int ra = wm * 64 + t * 16 + c16;
      af[t] = *(const sfrag*)(As + ra * 32 + ((quad ^ ((ra >> 1) & 3)) * 8));
      if (!BNN) {
        int rbt = wn * 64 + t * 16 + c16;
        bfr[t] = *(const sfrag*)(Bs + rbt * 32 + ((quad ^ ((rbt >> 1) & 3)) * 8));
      } else {
        int n_l = wn * 64 + t * 16 + c16;
        int cb = (n_l >> 3) ^ quad;
        int off = n_l & 7;
        sfrag v;
#pragma unroll
        for (int j = 0; j < 8; ++j)
          v[j] = Bs[(quad * 8 + j) * 128 + cb * 8 + off];
        bfr[t] = v;
      }
    }
#pragma unroll
    for (int mt = 0; mt < 4; ++mt)
#pragma unroll
      for (int nt = 0; nt < 4; ++nt)
        acc[mt][nt] = __builtin_amdgcn_mfma_f32_16x16x32_bf16(
            af[mt], bfr[nt], acc[mt][nt], 0, 0, 0);
  }
}

// ---------------- fused phase kernels (named fields, uniform selects) ----------
struct P1Args {
  const short *A0, *A1, *A2, *A3;
  const short *W0, *W1, *W2, *W3;
  const float *bias0, *bias1, *bias2, *bias3;
  const float *Xin0, *Xin1, *Xin2, *Xin3;
  short *E0, *E1, *E2, *E3;
  uint32_t k00, k01, k10, k11, k20, k21, k30, k31;
  float nscale;
};

__global__ __launch_bounds__(256) void phase1_k(P1Args p) {
  int b = blockIdx.x;
  int li = (b >= 448) ? ((b >= 704) ? 3 : 2) : ((b >= 192) ? 1 : 0);
  int local = b - (li == 0 ? 0 : li == 1 ? 192 : li == 2 ? 448 : 704);
  int m0 = (local & 7) << 7, n0 = (local >> 3) << 7;
  const int N = li == 0 ? 3072 : li == 1 ? 4096 : li == 2 ? 4096 : 2048;
  const int K = li == 0 ? 4096 : li == 1 ? 4096 : li == 2 ? 2048 : 1024;
  const short* A = li == 0 ? p.A0 : li == 1 ? p.A1 : li == 2 ? p.A2 : p.A3;
  const short* W = li == 0 ? p.W0 : li == 1 ? p.W1 : li == 2 ? p.W2 : p.W3;
  const float* bias = li == 0 ? p.bias0 : li == 1 ? p.bias1 : li == 2 ? p.bias2 : p.bias3;
  const float* Xin = li == 0 ? p.Xin0 : li == 1 ? p.Xin1 : li == 2 ? p.Xin2 : p.Xin3;
  short* Eo = li == 0 ? p.E0 : li == 1 ? p.E1 : li == 2 ? p.E2 : p.E3;
  const uint32_t K0 = li == 0 ? p.k00 : li == 1 ? p.k10 : li == 2 ? p.k20 : p.k30;
  const uint32_t K1 = li == 0 ? p.k01 : li == 1 ? p.k11 : li == 2 ? p.k21 : p.k31;

  __shared__ alignas(16) short As[128 * 32];
  __shared__ alignas(16) short Bs[128 * 32];
  f32x4 acc[4][4];
#pragma unroll
  for (int i = 0; i < 4; ++i)
#pragma unroll
    for (int j = 0; j < 4; ++j) acc[i][j] = (f32x4){0.f, 0.f, 0.f, 0.f};

  mfma_block<false>(A, W, K, K, m0, n0, As, Bs, acc);

  const int tid = threadIdx.x, ln = tid & 63, wv = tid >> 6;
  const int wm = wv >> 1, wn = wv & 1, c16 = ln & 15, quad = ln >> 4;
  const uint32_t halfn = (uint32_t)(((size_t)B_ROWS * (size_t)N) >> 1);
  const float ns = p.nscale;
#pragma unroll
  for (int mt = 0; mt < 4; ++mt)
#pragma unroll
    for (int nt = 0; nt < 4; ++nt)
#pragma unroll
      for (int rg = 0; rg < 4; ++rg) {
        int m = m0 + wm * 64 + mt * 16 + quad * 4 + rg;
        int n = n0 + wn * 64 + nt * 16 + c16;
        size_t jf = (size_t)m * N + n;
        float pred = acc[mt][nt][rg] + bias[n];
        float z = jax_normal_at((uint32_t)jf, halfn, K0, K1);
        Eo[jf] = f2bf(Xin[jf] - pred + z * ns);
      }
}

struct P2Args {
  const short *A0, *A1, *A2, *A3;
  const short *W0, *W1, *W2, *W3;
  const short *E0, *E1, *E2;       // E3 = null
  float *Xs0, *Xs1, *Xs2, *Xs3;
  short *T0, *T1, *T2, *T3;
};

template <bool BNN>
__global__ __launch_bounds__(256) void phase2_k(P2Args p) {
  int b = blockIdx.x;
  int li = (b >= 512) ? ((b >= 640) ? 3 : 2) : ((b >= 256) ? 1 : 0);
  int local = b - (li == 0 ? 0 : li == 1 ? 256 : li == 2 ? 512 : 640);
  int m0 = (local & 7) << 7, n0 = (local >> 3) << 7;
  const int N = li == 0 ? 4096 : li == 1 ? 4096 : li == 2 ? 2048 : 1024;
  const int Nlog = li == 0 ? 4096 : li == 1 ? 4096 : li == 2 ? 2048 : 1000;
  const int K = li == 0 ? 3072 : li == 1 ? 4096 : li == 2 ? 4096 : 2048;
  const int SB = BNN ? (li == 0 ? 4096 : li == 1 ? 4096 : li == 2 ? 2048 : 1024) : K;
  const short* A = li == 0 ? p.A0 : li == 1 ? p.A1 : li == 2 ? p.A2 : p.A3;
  const short* W = li == 0 ? p.W0 : li == 1 ? p.W1 : li == 2 ? p.W2 : p.W3;
  const short* Ep = li == 0 ? p.E0 : li == 1 ? p.E1 : li == 2 ? p.E2 : (const short*)nullptr;
  float* Xs = li == 0 ? p.Xs0 : li == 1 ? p.Xs1 : li == 2 ? p.Xs2 : p.Xs3;
  short* T = li == 0 ? p.T0 : li == 1 ? p.T1 : li == 2 ? p.T2 : p.T3;

  __shared__ alignas(16) short As[128 * 32];
  __shared__ alignas(16) short Bs[128 * 32];
  f32x4 acc[4][4];
#pragma unroll
  for (int i = 0; i < 4; ++i)
#pragma unroll
    for (int j = 0; j < 4; ++j) acc[i][j] = (f32x4){0.f, 0.f, 0.f, 0.f};

  mfma_block<BNN>(A, W, K, SB, m0, n0, As, Bs, acc);

  const int tid = threadIdx.x, ln = tid & 63, wv = tid >> 6;
  const int wm = wv >> 1, wn = wv & 1, c16 = ln & 15, quad = ln >> 4;
#pragma unroll
  for (int mt = 0; mt < 4; ++mt)
#pragma unroll
    for (int nt = 0; nt < 4; ++nt)
#pragma unroll
      for (int rg = 0; rg < 4; ++rg) {
        int m = m0 + wm * 64 + mt * 16 + quad * 4 + rg;
        int n = n0 + wn * 64 + nt * 16 + c16;
        if (n >= Nlog) continue;
        size_t jfX = (size_t)m * Nlog + n;
        float x = Xs[jfX];
        float t = tanhf(x);
        float e = Ep ? b2f(Ep[jfX]) : 0.f;
        float xn = x + GAMMA_F * fmaf(acc[mt][nt][rg], 1.0f - t * t, -e);
        Xs[jfX] = xn;
        T[(size_t)m * N + n] = f2bf(tanhf(xn));
      }
}

// init: C = A @ W; writes xs fp32, x bf16 (optional), tanh bf16
template <bool BNN>
__global__ __launch_bounds__(256) void gemm0_k(const short* __restrict__ A,
                                               const short* __restrict__ W,
                                               float* __restrict__ Xs,
                                               short* __restrict__ Xb,
                                               short* __restrict__ T,
                                               int Ngrid, int Nlog, int K, int SB) {
  int m0 = blockIdx.y << 7, n0 = blockIdx.x << 7;
  __shared__ alignas(16) short As[128 * 32];
  __shared__ alignas(16) short Bs[128 * 32];
  f32x4 acc[4][4];
#pragma unroll
  for (int i = 0; i < 4; ++i)
#pragma unroll
    for (int j = 0; j < 4; ++j) acc[i][j] = (f32x4){0.f, 0.f, 0.f, 0.f};

  mfma_block<BNN>(A, W, K, SB, m0, n0, As, Bs, acc);

  const int tid = threadIdx.x, ln = tid & 63, wv = tid >> 6;
  const int wm = wv >> 1, wn = wv & 1, c16 = ln & 15, quad = ln >> 4;
#pragma unroll
  for (int mt = 0; mt < 4; ++mt)
#pragma unroll
    for (int nt = 0; nt < 4; ++nt)
#pragma unroll
      for (int rg = 0; rg < 4; ++rg) {
        int m = m0 + wm * 64 + mt * 16 + quad * 4 + rg;
        int n = n0 + wn * 64 + nt * 16 + c16;
        if (n >= Nlog) continue;
        size_t jf = (size_t)m * Nlog + n;
        float x = acc[mt][nt][rg];
        Xs[jf] = x;
        if (Xb) Xb[jf] = f2bf(x);
        T[(size_t)m * Ngrid + n] = f2bf(tanhf(x));
      }
}

// ---------------- prep kernels ----------------
__global__ void cvt_k(const float* __restrict__ s, short* __restrict__ d, int n) {
  int i = blockIdx.x * blockDim.x + threadIdx.x;
  if (i < n) d[i] = f2bf(s[i]);
}

__global__ void cvt_pad_k(const float* __restrict__ s, short* __restrict__ d,
                          int R, int Cs, int sh) {
  int i = blockIdx.x * blockDim.x + threadIdx.x;
  int total = R << sh;
  if (i >= total) return;
  int r = i >> sh, c = i & ((1 << sh) - 1);
  d[i] = (c < Cs) ? f2bf(s[(size_t)r * Cs + c]) : (short)0;
}

__global__ void transpose_k(const float* __restrict__ s, short* __restrict__ d,
                            int R, int C) {
  __shared__ float tile[32][33];
  int cb = blockIdx.x * 32, rb = blockIdx.y * 32;
  int tx = threadIdx.x & 31, ty = threadIdx.x >> 5;
#pragma unroll
  for (int i = 0; i < 4; ++i) {
    int r = rb + ty + i * 8, c = cb + tx;
    if (c < C) tile[ty + i * 8][tx] = s[(size_t)r * C + c];
  }
  __syncthreads();
#pragma unroll
  for (int i = 0; i < 4; ++i) {
    int rr = rb + tx, cc = cb + ty + i * 8;
    if (cc < C) d[(size_t)cc * R + rr] = f2bf(tile[tx][ty + i * 8]);
  }
}

__global__ void zero_pad_k(short* __restrict__ t4) {
  int i = blockIdx.x * blockDim.x + threadIdx.x;
  int r = i >> 5, c = i & 31;
  if (r < 1024 && c < 24) t4[(size_t)r * 1024 + 1000 + c] = 0;
}

// ================= fp32 fallback (round-1, proven) =================
template <int MODE>
__global__ __launch_bounds__(256)
void gemm_k(const float* __restrict__ A, const float* __restrict__ W,
            const float* __restrict__ bias, const float* __restrict__ Xin,
            const float* __restrict__ E, float* __restrict__ out,
            int M, int N, int K,
            uint32_t key0, uint32_t key1, float nscale) {
  __shared__ float As[16][68];
  __shared__ float Bs[16][68];
  const int tid = threadIdx.x;
  const int m0 = blockIdx.y * 64;
  const int n0 = blockIdx.x * 64;
  const int tx = tid & 15;
  const int ty = tid >> 4;
  float acc[4][4] = {};
  for (int k0 = 0; k0 < K; k0 += 16) {
    {
      int m_l = tid >> 2;
      int k_l = (tid & 3) << 2;
      int gk = k0 + k_l;
      float4 v = make_float4(0.f, 0.f, 0.f, 0.f);
      if (gk < K) v = *reinterpret_cast<const float4*>(A + (size_t)(m0 + m_l) * K + gk);
      if (MODE == 1) { v.x = tanhf(v.x); v.y = tanhf(v.y); v.z = tanhf(v.z); v.w = tanhf(v.w); }
      As[k_l + 0][m_l] = v.x; As[k_l + 1][m_l] = v.y;
      As[k_l + 2][m_l] = v.z; As[k_l + 3][m_l] = v.w;
    }
    if (MODE == 1) {
      int n_l = tid >> 2;
      int k_l = (tid & 3) << 2;
      int gn = n0 + n_l, gk = k0 + k_l;
      float4 v = make_float4(0.f, 0.f, 0.f, 0.f);
      if (gn < N && gk < K) v = *reinterpret_cast<const float4*>(W + (size_t)gn * K + gk);
      Bs[k_l + 0][n_l] = v.x; Bs[k_l + 1][n_l] = v.y;
      Bs[k_l + 2][n_l] = v.z; Bs[k_l + 3][n_l] = v.w;
    } else {
      int k_l = tid >> 4;
      int n_l = (tid & 15) << 2;
      int gk = k0 + k_l, gn = n0 + n_l;
      float4 v = make_float4(0.f, 0.f, 0.f, 0.f);
      if (gk < K && gn < N) v = *reinterpret_cast<const float4*>(W + (size_t)gk * N + gn);
      *reinterpret_cast<float4*>(&Bs[k_l][n_l]) = v;
    }
    __syncthreads();
#pragma unroll
    for (int kk = 0; kk < 16; ++kk) {
      float4 a = *reinterpret_cast<const float4*>(&As[kk][ty << 2]);
      float4 b = *reinterpret_cast<const float4*>(&Bs[kk][tx << 2]);
      acc[0][0] = fmaf(a.x, b.x, acc[0][0]); acc[0][1] = fmaf(a.x, b.y, acc[0][1]);
      acc[0][2] = fmaf(a.x, b.z, acc[0][2]); acc[0][3] = fmaf(a.x, b.w, acc[0][3]);
      acc[1][0] = fmaf(a.y, b.x, acc[1][0]); acc[1][1] = fmaf(a.y, b.y, acc[1][1]);
      acc[1][2] = fmaf(a.y, b.z, acc[1][2]); acc[1][3] = fmaf(a.y, b.w, acc[1][3]);
      acc[2][0] = fmaf(a.z, b.x, acc[2][0]); acc[2][1] = fmaf(a.z, b.y, acc[2][1]);
      acc[2][2] = fmaf(a.z, b.z, acc[2][2]); acc[2][3] = fmaf(a.z, b.w, acc[2][3]);
      acc[3][0] = fmaf(a.w, b.x, acc[3][0]); acc[3][1] = fmaf(a.w, b.y, acc[3][1]);
      acc[3][2] = fmaf(a.w, b.z, acc[3][2]); acc[3][3] = fmaf(a.w, b.w, acc[3][3]);
    }
    __syncthreads();
  }
  const uint32_t half_n = (uint32_t)(((size_t)M * N) >> 1);
#pragma unroll
  for (int i = 0; i < 4; ++i) {
    int m = m0 + (ty << 2) + i;
#pragma unroll
    for (int jx = 0; jx < 4; ++jx) {
      int n = n0 + (tx << 2) + jx;
      if (n >= N) continue;
      size_t jf = (size_t)m * N + n;
      float a = acc[i][jx];
      if (MODE == 0) {
        out[jf] = a;
      } else if (MODE == 1) {
        float pred = a + bias[n];
        float z = jax_normal_at((uint32_t)jf, half_n, key0, key1);
        out[jf] = Xin[jf] - pred + z * nscale;
      } else {
        float x = out[jf];
        float t = tanhf(x);
        float e = (E != nullptr) ? E[jf] : 0.0f;
        out[jf] = x + GAMMA_F * fmaf(a, 1.0f - t * t, -e);
      }
    }
  }
}

// ---------------- launch ----------------
extern "C" void kernel_launch(void* const* d_in, const int* in_sizes, int n_in,
                              void* d_out, int out_size, void* d_ws, size_t ws_size,
                              hipStream_t stream) {
  const float* obs = (const float*)d_in[0];
  const float* W1  = (const float*)d_in[1];  // 3072 x 4096
  const float* b1  = (const float*)d_in[2];
  const float* W2  = (const float*)d_in[3];  // 4096 x 4096
  const float* b2  = (const float*)d_in[4];
  const float* W3  = (const float*)d_in[5];  // 4096 x 2048
  const float* b3  = (const float*)d_in[6];
  const float* W4  = (const float*)d_in[7];  // 2048 x 1000
  const float* b4  = (const float*)d_in[8];

  float* out = (float*)d_out;  // xs[4]: 1024 x 1000

  uint8_t* base = (uint8_t*)d_ws;
  size_t off = 0;
  auto alloc = [&](size_t bytes) -> size_t {
    size_t o = off;
    off = (off + bytes + 255) & ~(size_t)255;
    return o;
  };
  const size_t M = B_ROWS;
  size_t o_t1 = alloc(M * 4096 * 2), o_t2 = alloc(M * 4096 * 2);
  size_t o_t3 = alloc(M * 2048 * 2), o_t4 = alloc(M * 1024 * 2);
  size_t o_es0 = alloc(M * 3072 * 2), o_es1 = alloc(M * 4096 * 2);
  size_t o_es2 = alloc(M * 4096 * 2), o_es3 = alloc(M * 2048 * 2);
  size_t o_W1b = alloc((size_t)3072 * 4096 * 2), o_W2b = alloc((size_t)4096 * 4096 * 2);
  size_t o_W3b = alloc((size_t)4096 * 2048 * 2), o_W4b = alloc((size_t)2048 * 1024 * 2);
  size_t o_xs1 = alloc(M * 4096 * 4), o_xs2 = alloc(M * 4096 * 4);
  size_t o_xs3 = alloc(M * 2048 * 4);
  size_t need_B = off;
  size_t o_W1T = alloc((size_t)4096 * 3072 * 2), o_W2T = alloc((size_t)4096 * 4096 * 2);
  size_t o_W3T = alloc((size_t)2048 * 4096 * 2), o_W4T = alloc((size_t)1024 * 2048 * 2);
  size_t need_A = off;

  if (ws_size >= need_B) {
    const bool tierA = (ws_size >= need_A);
    short* t1 = (short*)(base + o_t1); short* t2 = (short*)(base + o_t2);
    short* t3 = (short*)(base + o_t3); short* t4 = (short*)(base + o_t4);
    short* es0 = (short*)(base + o_es0); short* es1 = (short*)(base + o_es1);
    short* es2 = (short*)(base + o_es2); short* es3 = (short*)(base + o_es3);
    short* W1b = (short*)(base + o_W1b); short* W2b = (short*)(base + o_W2b);
    short* W3b = (short*)(base + o_W3b); short* W4b = (short*)(base + o_W4b);
    float* xs1 = (float*)(base + o_xs1); float* xs2 = (float*)(base + o_xs2);
    float* xs3 = (float*)(base + o_xs3);
    short* W1T = (short*)(base + o_W1T); short* W2T = (short*)(base + o_W2T);
    short* W3T = (short*)(base + o_W3T); short* W4T = (short*)(base + o_W4T);

    short* obsb = es0;   // init scratch (overwritten each step)
    short* x1b = es1;
    short* x2b = es2;
    short* x3b = es3;

    {
      int n = (int)(M * 3072);
      cvt_k<<<(n + 255) / 256, 256, 0, stream>>>(obs, obsb, n);
    }
    cvt_pad_k<<<((3072 << 12) + 255) / 256, 256, 0, stream>>>(W1, W1b, 3072, 4096, 12);
    cvt_pad_k<<<((4096 << 12) + 255) / 256, 256, 0, stream>>>(W2, W2b, 4096, 4096, 12);
    cvt_pad_k<<<((4096 << 11) + 255) / 256, 256, 0, stream>>>(W3, W3b, 4096, 2048, 11);
    cvt_pad_k<<<((2048 << 10) + 255) / 256, 256, 0, stream>>>(W4, W4b, 2048, 1000, 10);
    if (tierA) {
      transpose_k<<<dim3(4096 / 32, 3072 / 32), 256, 0, stream>>>(W1, W1T, 3072, 4096);
      transpose_k<<<dim3(4096 / 32, 4096 / 32), 256, 0, stream>>>(W2, W2T, 4096, 4096);
      transpose_k<<<dim3(2048 / 32, 4096 / 32), 256, 0, stream>>>(W3, W3T, 4096, 2048);
      transpose_k<<<dim3(32, 2048 / 32), 256, 0, stream>>>(W4, W4T, 2048, 1000);
    }
    zero_pad_k<<<(1024 * 32) / 256, 256, 0, stream>>>(t4);

    if (tierA) {
      gemm0_k<false><<<dim3(32, 8), 256, 0, stream>>>(obsb, W1T, xs1, x1b, t1, 4096, 4096, 3072, 3072);
      gemm0_k<false><<<dim3(32, 8), 256, 0, stream>>>(x1b, W2T, xs2, x2b, t2, 4096, 4096, 4096, 4096);
      gemm0_k<false><<<dim3(16, 8), 256, 0, stream>>>(x2b, W3T, xs3, x3b, t3, 2048, 2048, 4096, 4096);
      gemm0_k<false><<<dim3(8, 8), 256, 0, stream>>>(x3b, W4T, out, nullptr, t4, 1024, 1000, 2048, 2048);
    } else {
      gemm0_k<true><<<dim3(32, 8), 256, 0, stream>>>(obsb, W1b, xs1, x1b, t1, 4096, 4096, 3072, 4096);
      gemm0_k<true><<<dim3(32, 8), 256, 0, stream>>>(x1b, W2b, xs2, x2b, t2, 4096, 4096, 4096, 4096);
      gemm0_k<true><<<dim3(16, 8), 256, 0, stream>>>(x2b, W3b, xs3, x3b, t3, 2048, 2048, 4096, 2048);
      gemm0_k<true><<<dim3(8, 8), 256, 0, stream>>>(x3b, W4b, out, nullptr, t4, 1024, 1000, 2048, 1024);
    }

    P1Args p1{};
    p1.A0 = t1; p1.A1 = t2; p1.A2 = t3; p1.A3 = t4;
    p1.W0 = W1b; p1.W1 = W2b; p1.W2 = W3b; p1.W3 = W4b;
    p1.bias0 = b1; p1.bias1 = b2; p1.bias2 = b3; p1.bias3 = b4;
    p1.Xin0 = obs; p1.Xin1 = xs1; p1.Xin2 = xs2; p1.Xin3 = xs3;
    p1.E0 = es0; p1.E1 = es1; p1.E2 = es2; p1.E3 = es3;

    P2Args p2{};
    p2.A0 = es0; p2.A1 = es1; p2.A2 = es2; p2.A3 = es3;
    if (tierA) { p2.W0 = W1T; p2.W1 = W2T; p2.W2 = W3T; p2.W3 = W4T; }
    else       { p2.W0 = W1b; p2.W1 = W2b; p2.W2 = W3b; p2.W3 = W4b; }
    p2.E0 = es1; p2.E1 = es2; p2.E2 = es3;
    p2.Xs0 = xs1; p2.Xs1 = xs2; p2.Xs2 = xs3; p2.Xs3 = out;
    p2.T0 = t1; p2.T1 = t2; p2.T2 = t3; p2.T3 = t4;

    for (int i = 0; i < STEPS; ++i) {
      float scale = NOISE_SCALE_F * (1.0f - (float)i / (float)STEPS);
      uint32_t s0 = 0u, s1 = (uint32_t)i;
      tf2x32(0u, 42u, s0, s1);
      uint32_t kk[4][2];
      for (int li = 0; li < 4; ++li) {
        uint32_t a = 0u, bb = (uint32_t)li;
        tf2x32(s0, s1, a, bb);
        kk[li][0] = a; kk[li][1] = bb;
      }
      p1.k00 = kk[0][0]; p1.k01 = kk[0][1];
      p1.k10 = kk[1][0]; p1.k11 = kk[1][1];
      p1.k20 = kk[2][0]; p1.k21 = kk[2][1];
      p1.k30 = kk[3][0]; p1.k31 = kk[3][1];
      p1.nscale = scale;
      phase1_k<<<832, 256, 0, stream>>>(p1);
      if (tierA) phase2_k<false><<<704, 256, 0, stream>>>(p2);
      else       phase2_k<true><<<704, 256, 0, stream>>>(p2);
    }
    return;
  }

  // =================== fp32 fallback ===================
  float* ws = (float*)d_ws;
  float* xs1 = ws;
  float* xs2 = xs1 + (size_t)B_ROWS * 4096;
  float* xs3 = xs2 + (size_t)B_ROWS * 4096;
  float* es0 = xs3 + (size_t)B_ROWS * 2048;
  float* es1 = es0 + (size_t)B_ROWS * 3072;
  float* es2 = es1 + (size_t)B_ROWS * 4096;
  float* es3 = es2 + (size_t)B_ROWS * 4096;

  dim3 blk(256);
  auto grid_for = [](int N) { return dim3((N + 63) / 64, B_ROWS / 64); };

  gemm_k<0><<<grid_for(4096), blk, 0, stream>>>(obs, W1, nullptr, nullptr, nullptr, xs1,
                                                B_ROWS, 4096, 3072, 0u, 0u, 0.f);
  gemm_k<0><<<grid_for(4096), blk, 0, stream>>>(xs1, W2, nullptr, nullptr, nullptr, xs2,
                                                B_ROWS, 4096, 4096, 0u, 0u, 0.f);
  gemm_k<0><<<grid_for(2048), blk, 0, stream>>>(xs2, W3, nullptr, nullptr, nullptr, xs3,
                                                B_ROWS, 2048, 4096, 0u, 0u, 0.f);
  gemm_k<0><<<grid_for(1000), blk, 0, stream>>>(xs3, W4, nullptr, nullptr, nullptr, out,
                                                B_ROWS, 1000, 2048, 0u, 0u, 0.f);

  for (int i = 0; i < STEPS; ++i) {
    float scale = NOISE_SCALE_F * (1.0f - (float)i / (float)STEPS);
    uint32_t s0 = 0u, s1 = (uint32_t)i;
    tf2x32(0u, 42u, s0, s1);
    uint32_t kk[4][2];
    for (int li = 0; li < 4; ++li) {
      uint32_t a = 0u, bb = (uint32_t)li;
      tf2x32(s0, s1, a, bb);
      kk[li][0] = a; kk[li][1] = bb;
    }
    gemm_k<1><<<grid_for(3072), blk, 0, stream>>>(xs1, W1, b1, obs, nullptr, es0,
                                                  B_ROWS, 3072, 4096, kk[0][0], kk[0][1], scale);
    gemm_k<1><<<grid_for(4096), blk, 0, stream>>>(xs2, W2, b2, xs1, nullptr, es1,
                                                  B_ROWS, 4096, 4096, kk[1][0], kk[1][1], scale);
    gemm_k<1><<<grid_for(4096), blk, 0, stream>>>(xs3, W3, b3, xs2, nullptr, es2,
                                                  B_ROWS, 4096, 2048, kk[2][0], kk[2][1], scale);
    gemm_k<1><<<grid_for(2048), blk, 0, stream>>>(out, W4, b4, xs3, nullptr, es3,
                                                  B_ROWS, 2048, 1000, kk[3][0], kk[3][1], scale);
    gemm_k<2><<<grid_for(4096), blk, 0, stream>>>(es0, W1, nullptr, nullptr, es1, xs1,
                                                  B_ROWS, 4096, 3072, 0u, 0u, 0.f);
    gemm_k<2><<<grid_for(4096), blk, 0, stream>>>(es1, W2, nullptr, nullptr, es2, xs2,
                                                  B_ROWS, 4096, 4096, 0u, 0u, 0.f);
    gemm_k<2><<<grid_for(2048), blk, 0, stream>>>(es2, W3, nullptr, nullptr, es3, xs3,
                                                  B_ROWS, 2048, 4096, 0u, 0u, 0.f);
    gemm_k<2><<<grid_for(1000), blk, 0, stream>>>(es3, W4, nullptr, nullptr, nullptr, out,
                                                  B_ROWS, 1000, 2048, 0u, 0u, 0.f);
  }
}